// Round 7
// baseline (9771.214 us; speedup 1.0000x reference)
//
#include <hip/hip_runtime.h>

typedef unsigned short ushort_t;
typedef unsigned int   uint_t;
typedef unsigned long long ulong_t;
typedef __attribute__((ext_vector_type(8))) short short8;
typedef __attribute__((ext_vector_type(4))) float floatx4;

#define NEGV -1000000000.0f

__device__ __forceinline__ float bf2f(ushort_t h){ return __uint_as_float(((uint_t)h)<<16); }
__device__ __forceinline__ ushort_t f2bf(float f){
  uint_t u = __float_as_uint(f);
  uint_t r = u + 0x7fffu + ((u>>16)&1u);
  return (ushort_t)(r>>16);
}
__device__ __forceinline__ float wredsum(float v){ for(int o=32;o;o>>=1) v += __shfl_xor(v,o); return v; }
__device__ __forceinline__ float wredmax(float v){ for(int o=32;o;o>>=1) v = fmaxf(v,__shfl_xor(v,o)); return v; }
__device__ __forceinline__ int   wredsumi(int v){ for(int o=32;o;o>>=1) v += __shfl_xor(v,o); return v; }

// ---------------------------------------------------------------------------
// dtype-adaptive conversion, vectorized x8. Probe once per block in wave 0.
// ---------------------------------------------------------------------------
__global__ void k_cvt8(const void* __restrict__ src, ushort_t* __restrict__ dst,
                       long n, const ushort_t* __restrict__ probe_src){
  __shared__ int sflag;
  if (threadIdx.x < 64){
    ushort_t u = probe_src[2*threadIdx.x];
    int e = (u>>7)&0xFF;
    int c = (e>=100 && e<=140) ? 1 : 0;
    c = wredsumi(c);
    if (threadIdx.x==0) sflag = (c>32) ? 1 : 0;
  }
  __syncthreads();
  bool isbf = (sflag!=0);
  long base = (blockIdx.x*256L + threadIdx.x)*8;
  if (base>=n) return;
  if (isbf){
    if (base+8<=n) *(uint4*)(dst+base) = *(const uint4*)((const ushort_t*)src+base);
    else for (long i=base;i<n;i++) dst[i]=((const ushort_t*)src)[i];
  } else {
    const float* s = (const float*)src;
    if (base+8<=n){
      float4 v0 = *(const float4*)(s+base);
      float4 v1 = *(const float4*)(s+base+4);
      ushort_t o[8] = {f2bf(v0.x),f2bf(v0.y),f2bf(v0.z),f2bf(v0.w),
                       f2bf(v1.x),f2bf(v1.y),f2bf(v1.z),f2bf(v1.w)};
      *(uint4*)(dst+base) = *(uint4*)o;
    } else {
      for (long i=base;i<n;i++) dst[i]=f2bf(s[i]);
    }
  }
}

__device__ __forceinline__ bool probe_is_bf16(const ushort_t* probe_src){
  int c=0;
  #pragma unroll 1
  for (int i=0;i<64;i++){
    ushort_t u = probe_src[2*i];
    int e = (u>>7)&0xFF;
    c += (e>=100 && e<=140) ? 1 : 0;
  }
  return c>32;
}

// ---------------------------------------------------------------------------
// small prep kernels
// ---------------------------------------------------------------------------
__global__ void k_lens(const int* __restrict__ ti, const int* __restrict__ li,
                       int* __restrict__ nonpad, int* __restrict__ text_len,
                       int* __restrict__ left_len){
  int b = blockIdx.x, t = threadIdx.x;
  nonpad[b*128+t] = (ti[b*128+t]!=0) ? 1 : 0;
  if (t==0){
    int c=0; for (int k2=0;k2<128;k2++) c += (ti[b*128+k2]!=0);
    text_len[b]=c;
    int l=0; for (int k2=0;k2<24;k2++) l += (li[b*24+k2]!=0);
    left_len[b]=l;
  }
}

__global__ void k_aspmean(const int* __restrict__ ai, const ushort_t* __restrict__ em,
                          float* __restrict__ asp_mean){
  int b = blockIdx.x;
  int idxs[5]; int cnt=0;
  for (int a=0;a<5;a++){ int ix=ai[b*5+a]; idxs[a]=ix; cnt += (ix!=0); }
  float inv = 1.0f/(float)cnt;
  for (int d=threadIdx.x; d<300; d+=128){
    float s=0.f;
    for (int a=0;a<5;a++) if (idxs[a]) s += bf2f(em[(long)idxs[a]*300+d]);
    asp_mean[b*300+d] = s*inv;
  }
}

__global__ void k_embs(const int* __restrict__ ti, const int* __restrict__ pi,
                       const int* __restrict__ asp_post,
                       const ushort_t* __restrict__ em, const ushort_t* __restrict__ pe,
                       const float* __restrict__ asp_mean, ushort_t* __restrict__ embs){
  int blk = blockIdx.x;
  int b = blk>>7, t = blk&127;
  int ap = asp_post[b];
  int tix = ti[b*128+t];
  int pix = pi[b*128+t];
  for (int col=threadIdx.x; col<336; col+=128){
    ushort_t v;
    if (col<300) v = (t==ap) ? f2bf(asp_mean[b*300+col]) : em[(long)tix*300+col];
    else if (col<330) v = pe[pix*30 + (col-300)];
    else v = 0;
    embs[(long)(b*128+t)*336 + col] = v;
  }
}

__global__ void k_padcopy(const ushort_t* __restrict__ src, ushort_t* __restrict__ dst,
                          int rows, int sk, int dk){
  int i = blockIdx.x*blockDim.x + threadIdx.x;
  int n = rows*dk;
  if (i<n){
    int r = i/dk, c2 = i - r*dk;
    dst[i] = (c2<sk) ? src[r*sk+c2] : 0;
  }
}

__global__ void k_biassum(const ushort_t* __restrict__ a, const ushort_t* __restrict__ b,
                          float* __restrict__ dst, int n){
  int i = blockIdx.x*blockDim.x + threadIdx.x;
  if (i<n) dst[i] = bf2f(a[i]) + bf2f(b[i]);
}
__global__ void k_biascvt(const ushort_t* __restrict__ a, float* __restrict__ dst, int n){
  int i = blockIdx.x*blockDim.x + threadIdx.x;
  if (i<n) dst[i] = bf2f(a[i]);
}

// ---------------------------------------------------------------------------
// generic bf16 MFMA GEMM: 128x128 tile, 4 waves (2x2), each 64x64 via 4x4
// frags of 16x16x32.  TB=1: C = A * B^T.  TB=0: C = A * B.
// MODE 1: bf16 store (opt bias/relu/rowscale)
// MODE 2: qk head-scatter bf16 store (bias), T=128, dk=100->104
// MODE 3: f32 store, *0.1 and nonpad column mask (attention scores)
// ---------------------------------------------------------------------------
template<int TB, int MODE>
__global__ __launch_bounds__(256) void gemm_k(
    int M, int N, int K,
    const ushort_t* __restrict__ A, long lda, long sAz,
    const ushort_t* __restrict__ B, long ldb, long sBz,
    float* __restrict__ Cf, ushort_t* __restrict__ Cb, long ldc, long sCz,
    const float* __restrict__ bias, int relu,
    const float* __restrict__ rowscale,
    const int* __restrict__ nonpad)
{
  __shared__ ushort_t As[128*40];
  __shared__ ushort_t Bs[128*40];
  const int tid = threadIdx.x;
  const int m0 = blockIdx.x*128, n0 = blockIdx.y*128;
  const int z = blockIdx.z;
  const ushort_t* Ap = A + (long)z*sAz;
  const ushort_t* Bp = B + (long)z*sBz;
  floatx4 acc[4][4];
  #pragma unroll
  for (int i=0;i<4;i++)
    #pragma unroll
    for (int j=0;j<4;j++){ acc[i][j][0]=0.f; acc[i][j][1]=0.f; acc[i][j][2]=0.f; acc[i][j][3]=0.f; }
  const int w = tid>>6, wm = w&1, wn = w>>1;
  const int lane = tid&63, lr = lane&15, lq = lane>>4;

  for (int k0=0;k0<K;k0+=32){
    #pragma unroll
    for (int c2=0;c2<2;c2++){
      int ch = tid + 256*c2;
      int row = ch>>2, kc = (ch&3)*8;
      int gr = m0+row, gk = k0+kc;
      uint4 v{};
      if (gr<M && gk<K) v = *(const uint4*)(Ap + (long)gr*lda + gk);
      *(uint4*)(&As[row*40+kc]) = v;
    }
    if (TB){
      #pragma unroll
      for (int c2=0;c2<2;c2++){
        int ch = tid + 256*c2;
        int row = ch>>2, kc = (ch&3)*8;
        int gn = n0+row, gk = k0+kc;
        uint4 v{};
        if (gn<N && gk<K) v = *(const uint4*)(Bp + (long)gn*ldb + gk);
        int sw = kc ^ (((row>>3)&3)<<3);
        *(uint4*)(&Bs[row*40+sw]) = v;
      }
    } else {
      #pragma unroll
      for (int c2=0;c2<2;c2++){
        int ch = tid + 256*c2;
        int kk = ch>>4, nc = (ch&15)*8;
        int gk = k0+kk, gn = n0+nc;
        uint4 v{};
        if (gk<K && gn<N) v = *(const uint4*)(Bp + (long)gk*ldb + gn);
        uint_t wsv[4] = {v.x, v.y, v.z, v.w};
        #pragma unroll
        for (int e=0;e<8;e++){
          ushort_t hv = (e&1) ? (ushort_t)(wsv[e>>1]>>16) : (ushort_t)(wsv[e>>1]&0xffffu);
          int n = nc+e;
          int sw = kk ^ (((n>>3)&3)<<3);
          Bs[n*40+sw] = hv;
        }
      }
    }
    __syncthreads();
    short8 af[4], bfv[4];
    #pragma unroll
    for (int i=0;i<4;i++) af[i] = *(const short8*)(&As[(wm*64+i*16+lr)*40 + lq*8]);
    #pragma unroll
    for (int j=0;j<4;j++){
      int n = wn*64+j*16+lr;
      int sw = (lq*8) ^ (((n>>3)&3)<<3);
      bfv[j] = *(const short8*)(&Bs[n*40+sw]);
    }
    #pragma unroll
    for (int i=0;i<4;i++)
      #pragma unroll
      for (int j=0;j<4;j++)
        acc[i][j] = __builtin_amdgcn_mfma_f32_16x16x32_bf16(af[i], bfv[j], acc[i][j], 0,0,0);
    __syncthreads();
  }

  #pragma unroll
  for (int i=0;i<4;i++){
    #pragma unroll
    for (int j=0;j<4;j++){
      #pragma unroll
      for (int r=0;r<4;r++){
        int row = m0 + wm*64 + i*16 + lq*4 + r;
        int col = n0 + wn*64 + j*16 + lr;
        if (row<M && col<N){
          float v = acc[i][j][r];
          if (rowscale) v *= rowscale[(long)z*M + row];
          if (bias) v += bias[col];
          if (relu && v<0.f) v = 0.f;
          if (MODE==1){
            Cb[(long)z*sCz + (long)row*ldc + col] = f2bf(v);
          } else if (MODE==2){
            int b = row>>7, t = row&127;
            int h = col/100, d = col - h*100;
            Cb[ ((long)((b*6+h)*128+t))*104 + d ] = f2bf(v);
          } else if (MODE==3){
            v *= 0.1f;
            if (!nonpad[(z/6)*128 + col]) v = NEGV;
            Cf[(long)z*sCz + (long)row*ldc + col] = v;
          }
        }
      }
    }
  }
}

// ---------------------------------------------------------------------------
// Persistent BiLSTM: 20 blocks (10 j-slices x 2 dirs), 128 steps internal.
// h exchange via 128 write-once per-step buffers: producers store with
// relaxed agent-scope atomics (write-through to L3); consumers use PLAIN
// cached loads -- safe because nobody ever cached those lines before the
// store (fresh buffer). Whh/gi stay L2-warm. gi prefetched into registers
// at step start. Per-dir relaxed grid barrier.
// ---------------------------------------------------------------------------
__global__ __launch_bounds__(256) void lstm_persist_k(
    const ushort_t* __restrict__ gi_f, const ushort_t* __restrict__ gi_b,
    const ushort_t* __restrict__ whh_f, const ushort_t* __restrict__ whh_b,
    ulong_t* __restrict__ hsteps,
    ushort_t* __restrict__ text_out, const int* __restrict__ text_len,
    int* __restrict__ bar)
{
  const int blk = blockIdx.x;
  const int dir = (blk>=10) ? 1 : 0;
  const int j0  = (blk%10)*32;
  const ushort_t* gi  = dir ? gi_b  : gi_f;
  const ushort_t* whh = dir ? whh_b : whh_f;
  const long HSTRIDE = 10752;            // qwords per step buffer (80KB+4KB guard)
  ulong_t* hb = hsteps + (long)dir*129*HSTRIDE;

  union LdsU {
    struct { ushort_t A[2][128*40]; ushort_t B[2][128*40]; } st;
    float g[64*132];
  };
  __shared__ LdsU u;

  const int tid = threadIdx.x;
  const int w = tid>>6, wm = w&1, wn = w>>1;
  const int lane = tid&63, lr = lane&15, lq = lane>>4;

  // staging geometry
  int srow[2], skc[2];
  long boff[2];
  bool bvalid[2];
  #pragma unroll
  for (int c2=0;c2<2;c2++){
    int ch = tid + 256*c2;
    srow[c2] = ch>>2; skc[c2] = (ch&3)*8;
    int gate = srow[c2]>>5; int j = j0 + (srow[c2]&31);
    bvalid[c2] = (j<300);
    boff[c2] = bvalid[c2] ? ((long)(gate*300+j)*320 + skc[c2]) : 0;
  }
  int swz[2];
  #pragma unroll
  for (int c2=0;c2<2;c2++) swz[c2] = skc[c2] ^ (((srow[c2]>>3)&3)<<3);

  const int jcol  = j0 + (tid&31);
  const int rbase = tid>>5;

  float c_reg[16], h_reg[16];
  #pragma unroll
  for (int i=0;i<16;i++){ c_reg[i]=0.f; h_reg[i]=0.f; }

  for (int s=0; s<128; s++){
    const int t = dir ? (127-s) : s;
    const ulong_t* hin  = hb + (long)s*HSTRIDE;
    ulong_t*       hout = hb + (long)(s+1)*HSTRIDE;

    floatx4 acc[4][4];
    #pragma unroll
    for (int i=0;i<4;i++)
      #pragma unroll
      for (int j=0;j<4;j++){ acc[i][j][0]=0.f; acc[i][j][1]=0.f; acc[i][j][2]=0.f; acc[i][j][3]=0.f; }

    uint4 pa[2], pb[2];
    // prologue: chunk 0 (plain cached loads; pad k [300,320) holds zeros)
    #pragma unroll
    for (int c2=0;c2<2;c2++){
      pa[c2] = *(const uint4*)(hin + (long)srow[c2]*80 + (skc[c2]>>2));
      uint4 v{};
      if (bvalid[c2]) v = *(const uint4*)(whh + boff[c2]);
      pb[c2] = v;
    }
    #pragma unroll
    for (int c2=0;c2<2;c2++){
      *(uint4*)(&u.st.A[0][srow[c2]*40+skc[c2]]) = pa[c2];
      *(uint4*)(&u.st.B[0][srow[c2]*40+swz[c2]]) = pb[c2];
    }
    __syncthreads();

    // gi register prefetch: 64 scalar loads, overlap the whole K-loop
    ushort_t gi_pre[16][4];
    #pragma unroll
    for (int idx=0; idx<16; idx++){
      int b = (idx>>3)*64 + rbase + (idx&7)*8;
      long gbase = (long)(b*128+t)*1200 + jcol;
      gi_pre[idx][0] = gi[gbase];
      gi_pre[idx][1] = gi[gbase+300];
      gi_pre[idx][2] = gi[gbase+600];
      gi_pre[idx][3] = gi[gbase+900];
    }

    for (int it=0; it<10; it++){
      int cur = it&1;
      if (it<9){
        int gk = (it+1)*32;
        #pragma unroll
        for (int c2=0;c2<2;c2++){
          pa[c2] = *(const uint4*)(hin + (long)srow[c2]*80 + ((gk+skc[c2])>>2));
          uint4 v{};
          if (bvalid[c2]) v = *(const uint4*)(whh + boff[c2] + gk);
          pb[c2] = v;
        }
      }
      short8 af[4], bfv[4];
      #pragma unroll
      for (int i=0;i<4;i++) af[i] = *(const short8*)(&u.st.A[cur][(wm*64+i*16+lr)*40 + lq*8]);
      #pragma unroll
      for (int j=0;j<4;j++){
        int n = wn*64+j*16+lr;
        int sw = (lq*8) ^ (((n>>3)&3)<<3);
        bfv[j] = *(const short8*)(&u.st.B[cur][n*40+sw]);
      }
      #pragma unroll
      for (int i=0;i<4;i++)
        #pragma unroll
        for (int j=0;j<4;j++)
          acc[i][j] = __builtin_amdgcn_mfma_f32_16x16x32_bf16(af[i], bfv[j], acc[i][j], 0,0,0);
      __syncthreads();
      if (it<9){
        #pragma unroll
        for (int c2=0;c2<2;c2++){
          *(uint4*)(&u.st.A[1-cur][srow[c2]*40+skc[c2]]) = pa[c2];
          *(uint4*)(&u.st.B[1-cur][srow[c2]*40+swz[c2]]) = pb[c2];
        }
        __syncthreads();
      }
    }

    // epilogue: transpose acc via LDS, gates, register h/c update, packed
    // qword write-through h store (shfl-pack with ALL lanes active so the
    // pad quads j in [300,320) store zeros)
    for (int p=0;p<2;p++){
      if (wm==p){
        #pragma unroll
        for (int i=0;i<4;i++)
          #pragma unroll
          for (int j=0;j<4;j++)
            #pragma unroll
            for (int r=0;r<4;r++)
              u.g[(i*16+lq*4+r)*132 + (wn*64+j*16+lr)] = acc[i][j][r];
      }
      __syncthreads();
      #pragma unroll
      for (int it2=0; it2<8; it2++){
        int item = tid + it2*256;
        int rl = item>>5, jp = item&31;
        int b = p*64 + rl;
        int j = j0 + jp;
        int idx = p*8 + it2;
        float hv = 0.f;
        if (j<300){
          float g_i = u.g[rl*132+jp]      + bf2f(gi_pre[idx][0]);
          float g_f = u.g[rl*132+32+jp]   + bf2f(gi_pre[idx][1]);
          float g_g = u.g[rl*132+64+jp]   + bf2f(gi_pre[idx][2]);
          float g_o = u.g[rl*132+96+jp]   + bf2f(gi_pre[idx][3]);
          float ig = 1.f/(1.f+expf(-g_i));
          float fg = 1.f/(1.f+expf(-g_f));
          float gg = tanhf(g_g);
          float og = 1.f/(1.f+expf(-g_o));
          float cn = fg*c_reg[idx] + ig*gg;
          float hn = og*tanhf(cn);
          int m = (t < text_len[b]) ? 1 : 0;
          if (m) c_reg[idx] = cn;
          hv = m ? hn : h_reg[idx];
          h_reg[idx] = hv;
          text_out[(long)(b*128+t)*600 + dir*300 + j] = f2bf(m ? hn : 0.f);
        }
        // all lanes active: pack 4 consecutive j into one qword
        uint_t hw32 = (uint_t)f2bf(hv);
        uint_t part = (uint_t)__shfl_xor((int)hw32, 1);
        uint_t w2b  = hw32 | (part<<16);
        uint_t hi2  = (uint_t)__shfl_xor((int)w2b, 2);
        if ((jp&3)==0){
          ulong_t qv = ((ulong_t)hi2<<32) | (ulong_t)w2b;
          __hip_atomic_store(hout + (long)b*80 + (j>>2), qv,
                             __ATOMIC_RELAXED, __HIP_MEMORY_SCOPE_AGENT);
        }
      }
      __syncthreads();
    }

    // per-dir relaxed grid barrier (per-step slot)
    if (s<127){
      asm volatile("s_waitcnt vmcnt(0)" ::: "memory");
      __syncthreads();
      if (tid==0){
        int slot = s*2 + dir;
        __hip_atomic_fetch_add(&bar[slot], 1, __ATOMIC_RELAXED, __HIP_MEMORY_SCOPE_AGENT);
        while (__hip_atomic_load(&bar[slot], __ATOMIC_RELAXED, __HIP_MEMORY_SCOPE_AGENT) < 10)
          __builtin_amdgcn_s_sleep(2);
      }
      __syncthreads();
    }
  }
}

// ---------------------------------------------------------------------------
// entmax15 over rows of 128 (in-place on f32 scores). 1 wave per row.
// ---------------------------------------------------------------------------
__global__ __launch_bounds__(64) void k_entmax(float* __restrict__ p){
  long row = blockIdx.x;
  float* base = p + row*128;
  __shared__ float xo[128], xs[128], c1[128], c2[128];
  int t = threadIdx.x;
  float a = base[t]*0.5f, b = base[t+64]*0.5f;
  float m = wredmax(fmaxf(a,b));
  a -= m; b -= m;
  xo[t]=a; xo[t+64]=b; xs[t]=a; xs[t+64]=b;
  __syncthreads();
  for (int k2=2;k2<=128;k2<<=1){
    for (int j=k2>>1;j>0;j>>=1){
      int i = ((t & ~(j-1))<<1) | (t & (j-1));
      int ixj = i | j;
      float vi = xs[i], vj = xs[ixj];
      bool blk = (i & k2)==0;
      bool sw = blk ? (vi < vj) : (vi > vj);
      __syncthreads();
      if (sw){ xs[i]=vj; xs[ixj]=vi; }
      __syncthreads();
    }
  }
  c1[t]=xs[t];       c2[t]=xs[t]*xs[t];
  c1[t+64]=xs[t+64]; c2[t+64]=xs[t+64]*xs[t+64];
  __syncthreads();
  for (int d=1; d<128; d<<=1){
    float a1 = (t>=d)     ? c1[t-d]    : 0.f;
    float a2 = (t>=d)     ? c2[t-d]    : 0.f;
    float b1 = (t+64>=d)  ? c1[t+64-d] : 0.f;
    float b2 = (t+64>=d)  ? c2[t+64-d] : 0.f;
    float x1=c1[t], y1=c2[t], x2=c1[t+64], y2=c2[t+64];
    __syncthreads();
    c1[t]=x1+a1; c2[t]=y1+a2; c1[t+64]=x2+b1; c2[t+64]=y2+b2;
    __syncthreads();
  }
  float tau_a, tau_b; int cnt=0;
  {
    float rho = (float)(t+1);
    float mean = c1[t]/rho, msq = c2[t]/rho;
    float ss = rho*(msq-mean*mean);
    float delta = (1.f-ss)/rho;
    tau_a = mean - sqrtf(fmaxf(delta,0.f));
    cnt += (tau_a <= xs[t]) ? 1 : 0;
  }
  {
    float rho = (float)(t+65);
    float mean = c1[t+64]/rho, msq = c2[t+64]/rho;
    float ss = rho*(msq-mean*mean);
    float delta = (1.f-ss)/rho;
    tau_b = mean - sqrtf(fmaxf(delta,0.f));
    cnt += (tau_b <= xs[t+64]) ? 1 : 0;
  }
  __syncthreads();
  c1[t]=tau_a; c1[t+64]=tau_b;
  __syncthreads();
  int support = wredsumi(cnt);
  support = (support<1) ? 1 : ((support>128) ? 128 : support);
  float tau_star = c1[support-1];
  float oa = fmaxf(xo[t]-tau_star, 0.f);
  float ob = fmaxf(xo[t+64]-tau_star, 0.f);
  base[t] = oa*oa; base[t+64] = ob*ob;
}

// ---------------------------------------------------------------------------
__global__ void k_adjsem(const float* __restrict__ p, const int* __restrict__ nonpad,
                         ushort_t* __restrict__ adj_sem){
  int idx = blockIdx.x*blockDim.x + threadIdx.x;
  if (idx >= 128*128*128) return;
  int b = idx>>14, rem = idx&16383, i = rem>>7, j = rem&127;
  float s = 0.f;
  for (int h=0;h<6;h++) s += p[(long)b*98304 + h*16384 + i*128 + j];
  float v = s/6.0f;
  if (i==j) v = 1.0f;
  if (!nonpad[b*128+i]) v = 0.f;
  adj_sem[idx] = f2bf(v);
}

__global__ __launch_bounds__(64) void k_dn(const ushort_t* __restrict__ src, float* __restrict__ dnv){
  long row = blockIdx.x;
  int l = threadIdx.x;
  float s = bf2f(src[row*128+l]) + bf2f(src[row*128+l+64]);
  s = wredsum(s);
  if (l==0) dnv[row] = 1.0f/sqrtf(s+1.0f);
}

__global__ __launch_bounds__(64) void k_mean(const ushort_t* __restrict__ X, float* __restrict__ ymean){
  long row = blockIdx.x;
  float s=0.f;
  for (int d=threadIdx.x; d<600; d+=64) s += bf2f(X[row*600+d]);
  s = wredsum(s);
  if (threadIdx.x==0) ymean[row] = s/600.0f;
}

__global__ void k_senet(const float* __restrict__ ymean,
                        const ushort_t* __restrict__ w1, const ushort_t* __restrict__ b1,
                        const ushort_t* __restrict__ w2, const ushort_t* __restrict__ b2,
                        const int* __restrict__ nonpad, float* __restrict__ ysoft){
  int b = blockIdx.x, t = threadIdx.x;
  __shared__ float yv[128], z1[12], red[128];
  yv[t] = ymean[b*128+t];
  __syncthreads();
  if (t<12){
    float s = bf2f(b1[t]);
    for (int k2=0;k2<128;k2++) s += yv[k2]*bf2f(w1[t*128+k2]);
    z1[t] = fmaxf(s,0.f);
  }
  __syncthreads();
  float v = bf2f(b2[t]);
  for (int r=0;r<12;r++) v += z1[r]*bf2f(w2[t*12+r]);
  if (!nonpad[b*128+t]) v += NEGV;
  red[t]=v; __syncthreads();
  for (int s2=64;s2>0;s2>>=1){ if (t<s2) red[t]=fmaxf(red[t],red[t+s2]); __syncthreads(); }
  float mx = red[0]; __syncthreads();
  float e = expf(v-mx);
  red[t]=e; __syncthreads();
  for (int s2=64;s2>0;s2>>=1){ if (t<s2) red[t]+=red[t+s2]; __syncthreads(); }
  float sm = red[0];
  ysoft[b*128+t] = e/sm;
}

__global__ void k_scale2(const ushort_t* __restrict__ X, const float* __restrict__ ysoft,
                         const float* __restrict__ dnv, ushort_t* __restrict__ out){
  int i = blockIdx.x*blockDim.x + threadIdx.x;
  if (i >= 128*128*600) return;
  int row = i/600;
  out[i] = f2bf(bf2f(X[i])*ysoft[row]*dnv[row]);
}

__global__ void k_gather(const ushort_t* __restrict__ X, const int* __restrict__ left_len,
                         ushort_t* __restrict__ dst){
  int b = blockIdx.x;
  int lb = left_len[b];
  for (int d=threadIdx.x; d<600; d+=128)
    dst[b*600+d] = X[(long)(b*128+lb)*600+d];
}

__global__ __launch_bounds__(256) void k_pool(const ushort_t* __restrict__ g,
                                              const ushort_t* __restrict__ X,
                                              float* __restrict__ pooled, int poff){
  int b = blockIdx.x, tid = threadIdx.x;
  __shared__ float gs[600], sbuf[128], red[256];
  for (int d=tid; d<600; d+=256) gs[d] = bf2f(g[b*600+d]);
  __syncthreads();
  int wv = tid>>6, lane = tid&63;
  for (int jj=wv; jj<128; jj+=4){
    float s=0.f;
    for (int d=lane; d<600; d+=64) s += gs[d]*bf2f(X[(long)(b*128+jj)*600+d]);
    s = wredsum(s);
    if (lane==0) sbuf[jj]=s;
  }
  __syncthreads();
  float v = (tid<128) ? sbuf[tid] : -3.4e38f;
  red[tid]=v; __syncthreads();
  for (int s2=128;s2>0;s2>>=1){ if (tid<s2) red[tid]=fmaxf(red[tid],red[tid+s2]); __syncthreads(); }
  float mx = red[0]; __syncthreads();
  float e = (tid<128) ? expf(v-mx) : 0.f;
  red[tid]=e; __syncthreads();
  for (int s2=128;s2>0;s2>>=1){ if (tid<s2) red[tid]+=red[tid+s2]; __syncthreads(); }
  float sm = red[0]; __syncthreads();
  if (tid<128) sbuf[tid] = e/sm;
  __syncthreads();
  for (int d=tid; d<600; d+=256){
    float acc=0.f;
    for (int j=0;j<128;j++) acc += sbuf[j]*bf2f(X[(long)(b*128+j)*600+d]);
    pooled[(long)b*1200 + poff + d] = acc;
  }
}

__global__ __launch_bounds__(64) void k_final(const float* __restrict__ pooled,
                                              const ushort_t* __restrict__ fcw,
                                              const ushort_t* __restrict__ fcb,
                                              void* __restrict__ out,
                                              const ushort_t* __restrict__ probe_src){
  bool isbf = probe_is_bf16(probe_src);
  int b = blockIdx.x, lane = threadIdx.x;
  for (int p=0;p<3;p++){
    float s=0.f;
    for (int d=lane; d<1200; d+=64) s += pooled[(long)b*1200+d]*bf2f(fcw[d*3+p]);
    s = wredsum(s);
    if (lane==0){
      float r = s + bf2f(fcb[p]);
      if (isbf) ((ushort_t*)out)[b*3+p] = f2bf(r);
      else      ((float*)out)[b*3+p] = r;
    }
  }
}

// ---------------------------------------------------------------------------
extern "C" void kernel_launch(void* const* d_in, const int* in_sizes, int n_in,
                              void* d_out, int out_size, void* d_ws, size_t ws_size,
                              hipStream_t stream) {
  const int*      ti   = (const int*)d_in[0];
  const int*      ai   = (const int*)d_in[1];
  const int*      li   = (const int*)d_in[2];
  const int*      pi   = (const int*)d_in[3];
  const int*      aps  = (const int*)d_in[4];
  const ushort_t* probe = (const ushort_t*)d_in[7];

  char* w = (char*)d_ws; size_t off = 0;
  auto alloc = [&](size_t bytes)->char*{ char* p = w+off; off = (off+bytes+255)&~(size_t)255; return p; };

  int*   bar      = (int*)alloc(1024);
  int*   text_len = (int*)alloc(512);
  int*   left_len = (int*)alloc(512);
  int*   nonpad   = (int*)alloc(65536);
  float* asp_mean = (float*)alloc(153600);
  float* dn1      = (float*)alloc(65536);
  float* dn2      = (float*)alloc(65536);
  float* ymean    = (float*)alloc(65536);
  float* ysoft    = (float*)alloc(65536);
  ulong_t* hsteps = (ulong_t*)alloc(22192128);  // 2 dirs x 129 bufs x 10752 qwords
  ushort_t* wihpf = (ushort_t*)alloc(806400);
  ushort_t* wihpb = (ushort_t*)alloc(806400);
  ushort_t* whhpf = (ushort_t*)alloc(768000);
  ushort_t* whhpb = (ushort_t*)alloc(768000);
  float* biasgf   = (float*)alloc(4800);
  float* biasgb   = (float*)alloc(4800);
  float* bqf      = (float*)alloc(2400);
  float* bkf      = (float*)alloc(2400);
  float* gc1bf    = (float*)alloc(2400);
  float* gc2bf    = (float*)alloc(2400);
  ushort_t* g1    = (ushort_t*)alloc(153600);
  ushort_t* g2    = (ushort_t*)alloc(153600);
  ushort_t* xr    = (ushort_t*)alloc(153600);
  ushort_t* xsr   = (ushort_t*)alloc(153600);
  float* pooled   = (float*)alloc(614400);
  ushort_t* adj_c  = (ushort_t*)alloc(4194304);
  ushort_t* pe_c   = (ushort_t*)alloc(2048);
  ushort_t* wihf_c = (ushort_t*)alloc(792000);
  ushort_t* wihb_c = (ushort_t*)alloc(792000);
  ushort_t* whhf_c = (ushort_t*)alloc(720000);
  ushort_t* whhb_c = (ushort_t*)alloc(720000);
  ushort_t* bihf_c = (ushort_t*)alloc(2400);
  ushort_t* bhhf_c = (ushort_t*)alloc(2400);
  ushort_t* bihb_c = (ushort_t*)alloc(2400);
  ushort_t* bhhb_c = (ushort_t*)alloc(2400);
  ushort_t* wq_c   = (ushort_t*)alloc(720000);
  ushort_t* bq_c   = (ushort_t*)alloc(1200);
  ushort_t* wk_c   = (ushort_t*)alloc(720000);
  ushort_t* bk_c   = (ushort_t*)alloc(1200);
  ushort_t* sw1_c  = (ushort_t*)alloc(3072);
  ushort_t* sb1_c  = (ushort_t*)alloc(256);
  ushort_t* sw2_c  = (ushort_t*)alloc(3072);
  ushort_t* sb2_c  = (ushort_t*)alloc(256);
  ushort_t* g1w_c  = (ushort_t*)alloc(720000);
  ushort_t* g1b_c  = (ushort_t*)alloc(1200);
  ushort_t* g2w_c  = (ushort_t*)alloc(720000);
  ushort_t* g2b_c  = (ushort_t*)alloc(1200);
  ushort_t* af1_c  = (ushort_t*)alloc(720000);
  ushort_t* af2_c  = (ushort_t*)alloc(720000);
  ushort_t* fcw_c  = (ushort_t*)alloc(7200);
  ushort_t* fcb_c  = (ushort_t*)alloc(256);
  ushort_t* embs  = (ushort_t*)alloc(11010048);
  ushort_t* textout = (ushort_t*)alloc(19660800);
  char* R = alloc(95420416);
  ushort_t* em_c    = (ushort_t*)(R);            // 18 MB; dead after k_embs
  ushort_t* gi_f    = (ushort_t*)(R);
  ushort_t* gi_b    = (ushort_t*)(R+39321600);
  ushort_t* qh      = (ushort_t*)(R);
  ushort_t* kh      = (ushort_t*)(R+20447232);
  float*    scores  = (float*)(R+40894464);
  ushort_t* adj_sem = (ushort_t*)(R+91226112);
  ushort_t* se_x    = (ushort_t*)(R+40894464);
  ushort_t* Zb      = (ushort_t*)(R+60555264);
  ushort_t* x_sem   = (ushort_t*)(R);
  ushort_t* xb      = (ushort_t*)(R+20447232);
  (void)ws_size; (void)n_in; (void)in_sizes; (void)out_size;

  // --- normalize all float inputs to bf16 (cheap per-block probe, x8 vec) ---
  {
    const int idx[27] = {7,6, 8,9,13,10,14,11,12,15,16,17,18,19,20,21,22,23,24,25,26,27,28,29,30,31,32};
    ushort_t* dl[27] = {em_c,adj_c, pe_c,wihf_c,wihb_c,whhf_c,whhb_c,bihf_c,bhhf_c,bihb_c,bhhb_c,
                        wq_c,bq_c,wk_c,bk_c,sw1_c,sb1_c,sw2_c,sb2_c,
                        g1w_c,g1b_c,g2w_c,g2b_c,af1_c,af2_c,fcw_c,fcb_c};
    const long nl[27] = {9000000L,2097152L, 900,396000,396000,360000,360000,1200,1200,1200,1200,
                         360000,600,360000,600,1536,12,1536,128,
                         360000,600,360000,600,360000,360000,3600,3};
    for (int i=0;i<27;i++){
      long nb = ((nl[i]+7)/8 + 255)/256;
      k_cvt8<<<(int)nb,256,0,stream>>>(d_in[idx[i]], dl[i], nl[i], probe);
    }
  }

  // --- init state: barrier slots + step-0 h buffers (both dirs) ---
  hipMemsetAsync(bar, 0, 1024, stream);
  hipMemsetAsync(hsteps, 0, 81920, stream);
  hipMemsetAsync(hsteps + 129L*10752L, 0, 81920, stream);

  // --- prep ---
  k_lens<<<128,128,0,stream>>>(ti, li, nonpad, text_len, left_len);
  k_aspmean<<<128,128,0,stream>>>(ai, em_c, asp_mean);
  k_embs<<<16384,128,0,stream>>>(ti, pi, aps, em_c, pe_c, asp_mean, embs);
  k_padcopy<<<(1200*336+255)/256,256,0,stream>>>(wihf_c, wihpf, 1200, 330, 336);
  k_padcopy<<<(1200*336+255)/256,256,0,stream>>>(wihb_c, wihpb, 1200, 330, 336);
  k_padcopy<<<(1200*320+255)/256,256,0,stream>>>(whhf_c, whhpf, 1200, 300, 320);
  k_padcopy<<<(1200*320+255)/256,256,0,stream>>>(whhb_c, whhpb, 1200, 300, 320);
  k_biassum<<<(1200+255)/256,256,0,stream>>>(bihf_c, bhhf_c, biasgf, 1200);
  k_biassum<<<(1200+255)/256,256,0,stream>>>(bihb_c, bhhb_c, biasgb, 1200);
  k_biascvt<<<3,256,0,stream>>>(bq_c, bqf, 600);
  k_biascvt<<<3,256,0,stream>>>(bk_c, bkf, 600);
  k_biascvt<<<3,256,0,stream>>>(g1b_c, gc1bf, 600);
  k_biascvt<<<3,256,0,stream>>>(g2b_c, gc2bf, 600);

  // --- input projections (embs @ Wih^T + bias) ---
  gemm_k<1,1><<<dim3(128,10,1),256,0,stream>>>(16384,1200,336, embs,336,0, wihpf,336,0,
        nullptr, gi_f,1200,0, biasgf,0,nullptr,nullptr);
  gemm_k<1,1><<<dim3(128,10,1),256,0,stream>>>(16384,1200,336, embs,336,0, wihpb,336,0,
        nullptr, gi_b,1200,0, biasgb,0,nullptr,nullptr);

  // --- BiLSTM: single persistent kernel, 128 steps internal ---
  lstm_persist_k<<<20,256,0,stream>>>(gi_f, gi_b, whhpf, whhpb,
        hsteps, textout, text_len, bar);

  // --- q/k projections, head-scattered (dk padded 100->104) ---
  hipMemsetAsync(qh, 0, 20447232, stream);
  hipMemsetAsync(kh, 0, 20447232, stream);
  gemm_k<1,2><<<dim3(128,5,1),256,0,stream>>>(16384,600,600, textout,600,0, wq_c,600,0,
        nullptr, qh,0,0, bqf,0,nullptr,nullptr);
  gemm_k<1,2><<<dim3(128,5,1),256,0,stream>>>(16384,600,600, textout,600,0, wk_c,600,0,
        nullptr, kh,0,0, bkf,0,nullptr,nullptr);

  // --- attention scores + mask ---
  gemm_k<1,3><<<dim3(1,1,768),256,0,stream>>>(128,128,104, qh,104,13312, kh,104,13312,
        scores, nullptr, 128, 16384, nullptr,0,nullptr, nonpad);

  // --- entmax15 (in place) ---
  k_entmax<<<98304,64,0,stream>>>(scores);

  // --- adjacency: head-mean + eye + valid; degree norms ---
  k_adjsem<<<(2097152+255)/256,256,0,stream>>>(scores, nonpad, adj_sem);
  k_dn<<<16384,64,0,stream>>>(adj_sem, dn1);
  k_dn<<<16384,64,0,stream>>>(adj_c, dn2);

  // --- SE #1 + GCN #1 (norm folded: Z = D (A (D * se * X))) ---
  k_mean<<<16384,64,0,stream>>>(textout, ymean);
  k_senet<<<128,128,0,stream>>>(ymean, sw1_c,sb1_c,sw2_c,sb2_c, nonpad, ysoft);
  k_scale2<<<(9830400+255)/256,256,0,stream>>>(textout, ysoft, dn1, se_x);
  gemm_k<0,1><<<dim3(1,5,128),256,0,stream>>>(128,600,128, adj_sem,128,16384, se_x,600,76800,
        nullptr, Zb,600,76800, nullptr,0, dn1, nullptr);
  gemm_k<0,1><<<dim3(128,5,1),256,0,stream>>>(16384,600,600, Zb,600,0, g1w_c,600,0,
        nullptr, x_sem,600,0, gc1bf,1,nullptr,nullptr);

  // --- SE #2 + GCN #2 (uses input adj) ---
  k_mean<<<16384,64,0,stream>>>(x_sem, ymean);
  k_senet<<<128,128,0,stream>>>(ymean, sw1_c,sb1_c,sw2_c,sb2_c, nonpad, ysoft);
  k_scale2<<<(9830400+255)/256,256,0,stream>>>(x_sem, ysoft, dn2, se_x);
  gemm_k<0,1><<<dim3(1,5,128),256,0,stream>>>(128,600,128, adj_c,128,16384, se_x,600,76800,
        nullptr, Zb,600,76800, nullptr,0, dn2, nullptr);
  gemm_k<0,1><<<dim3(128,5,1),256,0,stream>>>(16384,600,600, Zb,600,0, g2w_c,600,0,
        nullptr, xb,600,0, gc2bf,1,nullptr,nullptr);

  // --- biaffine pooling (only row left_len[b] of A1/A2 is ever used) ---
  k_gather<<<128,128,0,stream>>>(xb, left_len, xr);
  k_gather<<<128,128,0,stream>>>(x_sem, left_len, xsr);
  gemm_k<0,1><<<dim3(1,5,1),256,0,stream>>>(128,600,600, xr,600,0, af1_c,600,0,
        nullptr, g1,600,0, nullptr,0,nullptr,nullptr);
  gemm_k<0,1><<<dim3(1,5,1),256,0,stream>>>(128,600,600, xsr,600,0, af2_c,600,0,
        nullptr, g2,600,0, nullptr,0,nullptr,nullptr);
  k_pool<<<128,256,0,stream>>>(g1, x_sem, pooled, 0);
  k_pool<<<128,256,0,stream>>>(g2, xb, pooled, 600);

  // --- final FC (dtype-adaptive output) ---
  k_final<<<128,64,0,stream>>>(pooled, fcw_c, fcb_c, d_out, probe);
}

// Round 8
// 5193.332 us; speedup vs baseline: 1.8815x; 1.8815x over previous
//
#include <hip/hip_runtime.h>

typedef unsigned short ushort_t;
typedef unsigned int   uint_t;
typedef __attribute__((ext_vector_type(8))) short short8;
typedef __attribute__((ext_vector_type(4))) float floatx4;

#define NEGV -1000000000.0f

__device__ __forceinline__ float bf2f(ushort_t h){ return __uint_as_float(((uint_t)h)<<16); }
__device__ __forceinline__ ushort_t f2bf(float f){
  uint_t u = __float_as_uint(f);
  uint_t r = u + 0x7fffu + ((u>>16)&1u);
  return (ushort_t)(r>>16);
}
__device__ __forceinline__ float wredsum(float v){ for(int o=32;o;o>>=1) v += __shfl_xor(v,o); return v; }
__device__ __forceinline__ float wredmax(float v){ for(int o=32;o;o>>=1) v = fmaxf(v,__shfl_xor(v,o)); return v; }
__device__ __forceinline__ int   wredsumi(int v){ for(int o=32;o;o>>=1) v += __shfl_xor(v,o); return v; }

// ---------------------------------------------------------------------------
// dtype-adaptive conversion, vectorized x8. Probe once per block in wave 0.
// ---------------------------------------------------------------------------
__global__ void k_cvt8(const void* __restrict__ src, ushort_t* __restrict__ dst,
                       long n, const ushort_t* __restrict__ probe_src){
  __shared__ int sflag;
  if (threadIdx.x < 64){
    ushort_t u = probe_src[2*threadIdx.x];
    int e = (u>>7)&0xFF;
    int c = (e>=100 && e<=140) ? 1 : 0;
    c = wredsumi(c);
    if (threadIdx.x==0) sflag = (c>32) ? 1 : 0;
  }
  __syncthreads();
  bool isbf = (sflag!=0);
  long base = (blockIdx.x*256L + threadIdx.x)*8;
  if (base>=n) return;
  if (isbf){
    if (base+8<=n) *(uint4*)(dst+base) = *(const uint4*)((const ushort_t*)src+base);
    else for (long i=base;i<n;i++) dst[i]=((const ushort_t*)src)[i];
  } else {
    const float* s = (const float*)src;
    if (base+8<=n){
      float4 v0 = *(const float4*)(s+base);
      float4 v1 = *(const float4*)(s+base+4);
      ushort_t o[8] = {f2bf(v0.x),f2bf(v0.y),f2bf(v0.z),f2bf(v0.w),
                       f2bf(v1.x),f2bf(v1.y),f2bf(v1.z),f2bf(v1.w)};
      *(uint4*)(dst+base) = *(uint4*)o;
    } else {
      for (long i=base;i<n;i++) dst[i]=f2bf(s[i]);
    }
  }
}

__device__ __forceinline__ bool probe_is_bf16(const ushort_t* probe_src){
  int c=0;
  #pragma unroll 1
  for (int i=0;i<64;i++){
    ushort_t u = probe_src[2*i];
    int e = (u>>7)&0xFF;
    c += (e>=100 && e<=140) ? 1 : 0;
  }
  return c>32;
}

// ---------------------------------------------------------------------------
// small prep kernels
// ---------------------------------------------------------------------------
__global__ void k_lens(const int* __restrict__ ti, const int* __restrict__ li,
                       int* __restrict__ nonpad, int* __restrict__ text_len,
                       int* __restrict__ left_len){
  int b = blockIdx.x, t = threadIdx.x;
  nonpad[b*128+t] = (ti[b*128+t]!=0) ? 1 : 0;
  if (t==0){
    int c=0; for (int k2=0;k2<128;k2++) c += (ti[b*128+k2]!=0);
    text_len[b]=c;
    int l=0; for (int k2=0;k2<24;k2++) l += (li[b*24+k2]!=0);
    left_len[b]=l;
  }
}

__global__ void k_aspmean(const int* __restrict__ ai, const ushort_t* __restrict__ em,
                          float* __restrict__ asp_mean){
  int b = blockIdx.x;
  int idxs[5]; int cnt=0;
  for (int a=0;a<5;a++){ int ix=ai[b*5+a]; idxs[a]=ix; cnt += (ix!=0); }
  float inv = 1.0f/(float)cnt;
  for (int d=threadIdx.x; d<300; d+=128){
    float s=0.f;
    for (int a=0;a<5;a++) if (idxs[a]) s += bf2f(em[(long)idxs[a]*300+d]);
    asp_mean[b*300+d] = s*inv;
  }
}

__global__ void k_embs(const int* __restrict__ ti, const int* __restrict__ pi,
                       const int* __restrict__ asp_post,
                       const ushort_t* __restrict__ em, const ushort_t* __restrict__ pe,
                       const float* __restrict__ asp_mean, ushort_t* __restrict__ embs){
  int blk = blockIdx.x;
  int b = blk>>7, t = blk&127;
  int ap = asp_post[b];
  int tix = ti[b*128+t];
  int pix = pi[b*128+t];
  for (int col=threadIdx.x; col<336; col+=128){
    ushort_t v;
    if (col<300) v = (t==ap) ? f2bf(asp_mean[b*300+col]) : em[(long)tix*300+col];
    else if (col<330) v = pe[pix*30 + (col-300)];
    else v = 0;
    embs[(long)(b*128+t)*336 + col] = v;
  }
}

__global__ void k_padcopy(const ushort_t* __restrict__ src, ushort_t* __restrict__ dst,
                          int rows, int sk, int dk){
  int i = blockIdx.x*blockDim.x + threadIdx.x;
  int n = rows*dk;
  if (i<n){
    int r = i/dk, c2 = i - r*dk;
    dst[i] = (c2<sk) ? src[r*sk+c2] : 0;
  }
}

// Whh repack for the LSTM block kernel: dst[4][304][320], per-gate rows
// padded 300->304 and K padded 300->320 with zeros.
__global__ void k_padwhh(const ushort_t* __restrict__ src, ushort_t* __restrict__ dst){
  int i = blockIdx.x*blockDim.x + threadIdx.x;
  if (i >= 1216*320) return;
  int r = i/320, k = i - r*320;
  int gate = r/304, jj = r - gate*304;
  ushort_t v = 0;
  if (jj<300 && k<300) v = src[(long)(gate*300+jj)*300 + k];
  dst[i] = v;
}

__global__ void k_biassum(const ushort_t* __restrict__ a, const ushort_t* __restrict__ b,
                          float* __restrict__ dst, int n){
  int i = blockIdx.x*blockDim.x + threadIdx.x;
  if (i<n) dst[i] = bf2f(a[i]) + bf2f(b[i]);
}
__global__ void k_biascvt(const ushort_t* __restrict__ a, float* __restrict__ dst, int n){
  int i = blockIdx.x*blockDim.x + threadIdx.x;
  if (i<n) dst[i] = bf2f(a[i]);
}

// ---------------------------------------------------------------------------
// generic bf16 MFMA GEMM: 128x128 tile, 4 waves (2x2), each 64x64 via 4x4
// frags of 16x16x32.  TB=1: C = A * B^T.  TB=0: C = A * B.
// MODE 1: bf16 store (opt bias/relu/rowscale)
// MODE 2: qk head-scatter bf16 store (bias), T=128, dk=100->104
// MODE 3: f32 store, *0.1 and nonpad column mask (attention scores)
// ---------------------------------------------------------------------------
template<int TB, int MODE>
__global__ __launch_bounds__(256) void gemm_k(
    int M, int N, int K,
    const ushort_t* __restrict__ A, long lda, long sAz,
    const ushort_t* __restrict__ B, long ldb, long sBz,
    float* __restrict__ Cf, ushort_t* __restrict__ Cb, long ldc, long sCz,
    const float* __restrict__ bias, int relu,
    const float* __restrict__ rowscale,
    const int* __restrict__ nonpad)
{
  __shared__ ushort_t As[128*40];
  __shared__ ushort_t Bs[128*40];
  const int tid = threadIdx.x;
  const int m0 = blockIdx.x*128, n0 = blockIdx.y*128;
  const int z = blockIdx.z;
  const ushort_t* Ap = A + (long)z*sAz;
  const ushort_t* Bp = B + (long)z*sBz;
  floatx4 acc[4][4];
  #pragma unroll
  for (int i=0;i<4;i++)
    #pragma unroll
    for (int j=0;j<4;j++){ acc[i][j][0]=0.f; acc[i][j][1]=0.f; acc[i][j][2]=0.f; acc[i][j][3]=0.f; }
  const int w = tid>>6, wm = w&1, wn = w>>1;
  const int lane = tid&63, lr = lane&15, lq = lane>>4;

  for (int k0=0;k0<K;k0+=32){
    #pragma unroll
    for (int c2=0;c2<2;c2++){
      int ch = tid + 256*c2;
      int row = ch>>2, kc = (ch&3)*8;
      int gr = m0+row, gk = k0+kc;
      uint4 v{};
      if (gr<M && gk<K) v = *(const uint4*)(Ap + (long)gr*lda + gk);
      *(uint4*)(&As[row*40+kc]) = v;
    }
    if (TB){
      #pragma unroll
      for (int c2=0;c2<2;c2++){
        int ch = tid + 256*c2;
        int row = ch>>2, kc = (ch&3)*8;
        int gn = n0+row, gk = k0+kc;
        uint4 v{};
        if (gn<N && gk<K) v = *(const uint4*)(Bp + (long)gn*ldb + gk);
        int sw = kc ^ (((row>>3)&3)<<3);
        *(uint4*)(&Bs[row*40+sw]) = v;
      }
    } else {
      #pragma unroll
      for (int c2=0;c2<2;c2++){
        int ch = tid + 256*c2;
        int kk = ch>>4, nc = (ch&15)*8;
        int gk = k0+kk, gn = n0+nc;
        uint4 v{};
        if (gk<K && gn<N) v = *(const uint4*)(Bp + (long)gk*ldb + gn);
        uint_t wsv[4] = {v.x, v.y, v.z, v.w};
        #pragma unroll
        for (int e=0;e<8;e++){
          ushort_t hv = (e&1) ? (ushort_t)(wsv[e>>1]>>16) : (ushort_t)(wsv[e>>1]&0xffffu);
          int n = nc+e;
          int sw = kk ^ (((n>>3)&3)<<3);
          Bs[n*40+sw] = hv;
        }
      }
    }
    __syncthreads();
    short8 af[4], bfv[4];
    #pragma unroll
    for (int i=0;i<4;i++) af[i] = *(const short8*)(&As[(wm*64+i*16+lr)*40 + lq*8]);
    #pragma unroll
    for (int j=0;j<4;j++){
      int n = wn*64+j*16+lr;
      int sw = (lq*8) ^ (((n>>3)&3)<<3);
      bfv[j] = *(const short8*)(&Bs[n*40+sw]);
    }
    #pragma unroll
    for (int i=0;i<4;i++)
      #pragma unroll
      for (int j=0;j<4;j++)
        acc[i][j] = __builtin_amdgcn_mfma_f32_16x16x32_bf16(af[i], bfv[j], acc[i][j], 0,0,0);
    __syncthreads();
  }

  #pragma unroll
  for (int i=0;i<4;i++){
    #pragma unroll
    for (int j=0;j<4;j++){
      #pragma unroll
      for (int r=0;r<4;r++){
        int row = m0 + wm*64 + i*16 + lq*4 + r;
        int col = n0 + wn*64 + j*16 + lr;
        if (row<M && col<N){
          float v = acc[i][j][r];
          if (rowscale) v *= rowscale[(long)z*M + row];
          if (bias) v += bias[col];
          if (relu && v<0.f) v = 0.f;
          if (MODE==1){
            Cb[(long)z*sCz + (long)row*ldc + col] = f2bf(v);
          } else if (MODE==2){
            int b = row>>7, t = row&127;
            int h = col/100, d = col - h*100;
            Cb[ ((long)((b*6+h)*128+t))*104 + d ] = f2bf(v);
          } else if (MODE==3){
            v *= 0.1f;
            if (!nonpad[(z/6)*128 + col]) v = NEGV;
            Cf[(long)z*sCz + (long)row*ldc + col] = v;
          }
        }
      }
    }
  }
}

// ---------------------------------------------------------------------------
// Communication-free BiLSTM: grid 16 = 8 batch-groups x 2 dirs; block 256
// (4 waves). Each block owns 16 batches for all 128 steps; h and c live in
// LDS only. Wave w computes gate w: G[j,b] = Whh_w[j,:] . h[b,:] via MFMA
// with A-fragments loaded DIRECTLY from global (Whh stays L2-resident) and
// B-fragments (h) from LDS. Gate exchange via LDS g-buffer. No atomics,
// no grid barrier, no cross-block state.
// whh layout: [4][304][320] (per-gate rows padded, K padded, zeros).
// ---------------------------------------------------------------------------
__global__ __launch_bounds__(256) void lstm_block_k(
    const ushort_t* __restrict__ gi_f, const ushort_t* __restrict__ gi_b,
    const ushort_t* __restrict__ whh_f, const ushort_t* __restrict__ whh_b,
    ushort_t* __restrict__ text_out, const int* __restrict__ text_len)
{
  const int bx = blockIdx.x;
  const int dir = bx>>3, bg = bx&7;
  const ushort_t* gi  = dir ? gi_b  : gi_f;
  const ushort_t* whh = dir ? whh_b : whh_f;

  __shared__ __align__(16) ushort_t h_lds[16][328];   // k pad [300,328) = 0
  __shared__ __align__(16) float    c_lds[16][304];
  __shared__ __align__(16) float    g_lds[4][16][308];
  __shared__ int s_tlen[16];

  const int tid = threadIdx.x;
  const int w = tid>>6, lane = tid&63, lr = lane&15, lq = lane>>4;

  // init
  for (int i=tid; i<16*328; i+=256) ((ushort_t*)h_lds)[i] = 0;
  for (int i=tid; i<16*304; i+=256) ((float*)c_lds)[i] = 0.f;
  if (tid<16) s_tlen[tid] = text_len[bg*16+tid];
  __syncthreads();

  for (int s=0; s<128; s++){
    const int t = dir ? (127-s) : s;

    // gi register prefetch (independent of h; overlaps MFMA phase)
    ushort_t gp[19][4];
    #pragma unroll
    for (int it=0; it<19; it++){
      int item = tid + it*256;
      if (item<4800){
        int b = item/300, j = item - b*300;
        long gb = ((long)((bg*16+b)*128 + t))*1200 + j;
        gp[it][0] = gi[gb];
        gp[it][1] = gi[gb+300];
        gp[it][2] = gi[gb+600];
        gp[it][3] = gi[gb+900];
      }
    }

    // B-fragments: h rows (b = lane&15), 10 K-tiles
    short8 bfv[10];
    #pragma unroll
    for (int kt=0; kt<10; kt++)
      bfv[kt] = *(const short8*)(&h_lds[lr][kt*32 + lq*8]);

    // MFMA: wave w = gate w, 19 j-tiles x 10 K-tiles, A direct from global
    const ushort_t* wbase = whh + (long)w*304*320;
    #pragma unroll 1
    for (int nt=0; nt<19; nt++){
      floatx4 acc; acc[0]=0.f; acc[1]=0.f; acc[2]=0.f; acc[3]=0.f;
      const ushort_t* arow = wbase + (long)(nt*16 + lr)*320 + lq*8;
      #pragma unroll
      for (int kt=0; kt<10; kt++){
        short8 af = *(const short8*)(arow + kt*32);
        acc = __builtin_amdgcn_mfma_f32_16x16x32_bf16(af, bfv[kt], acc, 0,0,0);
      }
      // D: col=b=lane&15, row j = nt*16 + lq*4 + r  -> float4 store
      *(float4*)(&g_lds[w][lr][nt*16 + lq*4]) = *(float4*)&acc;
    }
    __syncthreads();

    // epilogue: gates, c/h update (LDS), text_out store
    #pragma unroll
    for (int it=0; it<19; it++){
      int item = tid + it*256;
      if (item<4800){
        int b = item/300, j = item - b*300;
        float g_i = g_lds[0][b][j] + bf2f(gp[it][0]);
        float g_f = g_lds[1][b][j] + bf2f(gp[it][1]);
        float g_g = g_lds[2][b][j] + bf2f(gp[it][2]);
        float g_o = g_lds[3][b][j] + bf2f(gp[it][3]);
        float ig = 1.f/(1.f+expf(-g_i));
        float fg = 1.f/(1.f+expf(-g_f));
        float gg = tanhf(g_g);
        float og = 1.f/(1.f+expf(-g_o));
        float cn = fg*c_lds[b][j] + ig*gg;
        float hn = og*tanhf(cn);
        int m = (t < s_tlen[b]) ? 1 : 0;
        if (m) c_lds[b][j] = cn;
        float hold = bf2f(h_lds[b][j]);
        float hv = m ? hn : hold;
        h_lds[b][j] = f2bf(hv);
        text_out[((long)((bg*16+b)*128+t))*600 + dir*300 + j] = f2bf(m ? hn : 0.f);
      }
    }
    __syncthreads();
  }
}

// ---------------------------------------------------------------------------
// entmax15 over rows of 128 (in-place on f32 scores). 1 wave per row.
// ---------------------------------------------------------------------------
__global__ __launch_bounds__(64) void k_entmax(float* __restrict__ p){
  long row = blockIdx.x;
  float* base = p + row*128;
  __shared__ float xo[128], xs[128], c1[128], c2[128];
  int t = threadIdx.x;
  float a = base[t]*0.5f, b = base[t+64]*0.5f;
  float m = wredmax(fmaxf(a,b));
  a -= m; b -= m;
  xo[t]=a; xo[t+64]=b; xs[t]=a; xs[t+64]=b;
  __syncthreads();
  for (int k2=2;k2<=128;k2<<=1){
    for (int j=k2>>1;j>0;j>>=1){
      int i = ((t & ~(j-1))<<1) | (t & (j-1));
      int ixj = i | j;
      float vi = xs[i], vj = xs[ixj];
      bool blk = (i & k2)==0;
      bool sw = blk ? (vi < vj) : (vi > vj);
      __syncthreads();
      if (sw){ xs[i]=vj; xs[ixj]=vi; }
      __syncthreads();
    }
  }
  c1[t]=xs[t];       c2[t]=xs[t]*xs[t];
  c1[t+64]=xs[t+64]; c2[t+64]=xs[t+64]*xs[t+64];
  __syncthreads();
  for (int d=1; d<128; d<<=1){
    float a1 = (t>=d)     ? c1[t-d]    : 0.f;
    float a2 = (t>=d)     ? c2[t-d]    : 0.f;
    float b1 = (t+64>=d)  ? c1[t+64-d] : 0.f;
    float b2 = (t+64>=d)  ? c2[t+64-d] : 0.f;
    float x1=c1[t], y1=c2[t], x2=c1[t+64], y2=c2[t+64];
    __syncthreads();
    c1[t]=x1+a1; c2[t]=y1+a2; c1[t+64]=x2+b1; c2[t+64]=y2+b2;
    __syncthreads();
  }
  float tau_a, tau_b; int cnt=0;
  {
    float rho = (float)(t+1);
    float mean = c1[t]/rho, msq = c2[t]/rho;
    float ss = rho*(msq-mean*mean);
    float delta = (1.f-ss)/rho;
    tau_a = mean - sqrtf(fmaxf(delta,0.f));
    cnt += (tau_a <= xs[t]) ? 1 : 0;
  }
  {
    float rho = (float)(t+65);
    float mean = c1[t+64]/rho, msq = c2[t+64]/rho;
    float ss = rho*(msq-mean*mean);
    float delta = (1.f-ss)/rho;
    tau_b = mean - sqrtf(fmaxf(delta,0.f));
    cnt += (tau_b <= xs[t+64]) ? 1 : 0;
  }
  __syncthreads();
  c1[t]=tau_a; c1[t+64]=tau_b;
  __syncthreads();
  int support = wredsumi(cnt);
  support = (support<1) ? 1 : ((support>128) ? 128 : support);
  float tau_star = c1[support-1];
  float oa = fmaxf(xo[t]-tau_star, 0.f);
  float ob = fmaxf(xo[t+64]-tau_star, 0.f);
  base[t] = oa*oa; base[t+64] = ob*ob;
}

// ---------------------------------------------------------------------------
__global__ void k_adjsem(const float* __restrict__ p, const int* __restrict__ nonpad,
                         ushort_t* __restrict__ adj_sem){
  int idx = blockIdx.x*blockDim.x + threadIdx.x;
  if (idx >= 128*128*128) return;
  int b = idx>>14, rem = idx&16383, i = rem>>7, j = rem&127;
  float s = 0.f;
  for (int h=0;h<6;h++) s += p[(long)b*98304 + h*16384 + i*128 + j];
  float v = s/6.0f;
  if (i==j) v = 1.0f;
  if (!nonpad[b*128+i]) v = 0.f;
  adj_sem[idx] = f2bf(v);
}

__global__ __launch_bounds__(64) void k_dn(const ushort_t* __restrict__ src, float* __restrict__ dnv){
  long row = blockIdx.x;
  int l = threadIdx.x;
  float s = bf2f(src[row*128+l]) + bf2f(src[row*128+l+64]);
  s = wredsum(s);
  if (l==0) dnv[row] = 1.0f/sqrtf(s+1.0f);
}

__global__ __launch_bounds__(64) void k_mean(const ushort_t* __restrict__ X, float* __restrict__ ymean){
  long row = blockIdx.x;
  float s=0.f;
  for (int d=threadIdx.x; d<600; d+=64) s += bf2f(X[row*600+d]);
  s = wredsum(s);
  if (threadIdx.x==0) ymean[row] = s/600.0f;
}

__global__ void k_senet(const float* __restrict__ ymean,
                        const ushort_t* __restrict__ w1, const ushort_t* __restrict__ b1,
                        const ushort_t* __restrict__ w2, const ushort_t* __restrict__ b2,
                        const int* __restrict__ nonpad, float* __restrict__ ysoft){
  int b = blockIdx.x, t = threadIdx.x;
  __shared__ float yv[128], z1[12], red[128];
  yv[t] = ymean[b*128+t];
  __syncthreads();
  if (t<12){
    float s = bf2f(b1[t]);
    for (int k2=0;k2<128;k2++) s += yv[k2]*bf2f(w1[t*128+k2]);
    z1[t] = fmaxf(s,0.f);
  }
  __syncthreads();
  float v = bf2f(b2[t]);
  for (int r=0;r<12;r++) v += z1[r]*bf2f(w2[t*12+r]);
  if (!nonpad[b*128+t]) v += NEGV;
  red[t]=v; __syncthreads();
  for (int s2=64;s2>0;s2>>=1){ if (t<s2) red[t]=fmaxf(red[t],red[t+s2]); __syncthreads(); }
  float mx = red[0]; __syncthreads();
  float e = expf(v-mx);
  red[t]=e; __syncthreads();
  for (int s2=64;s2>0;s2>>=1){ if (t<s2) red[t]+=red[t+s2]; __syncthreads(); }
  float sm = red[0];
  ysoft[b*128+t] = e/sm;
}

__global__ void k_scale2(const ushort_t* __restrict__ X, const float* __restrict__ ysoft,
                         const float* __restrict__ dnv, ushort_t* __restrict__ out){
  int i = blockIdx.x*blockDim.x + threadIdx.x;
  if (i >= 128*128*600) return;
  int row = i/600;
  out[i] = f2bf(bf2f(X[i])*ysoft[row]*dnv[row]);
}

__global__ void k_gather(const ushort_t* __restrict__ X, const int* __restrict__ left_len,
                         ushort_t* __restrict__ dst){
  int b = blockIdx.x;
  int lb = left_len[b];
  for (int d=threadIdx.x; d<600; d+=128)
    dst[b*600+d] = X[(long)(b*128+lb)*600+d];
}

__global__ __launch_bounds__(256) void k_pool(const ushort_t* __restrict__ g,
                                              const ushort_t* __restrict__ X,
                                              float* __restrict__ pooled, int poff){
  int b = blockIdx.x, tid = threadIdx.x;
  __shared__ float gs[600], sbuf[128], red[256];
  for (int d=tid; d<600; d+=256) gs[d] = bf2f(g[b*600+d]);
  __syncthreads();
  int wv = tid>>6, lane = tid&63;
  for (int jj=wv; jj<128; jj+=4){
    float s=0.f;
    for (int d=lane; d<600; d+=64) s += gs[d]*bf2f(X[(long)(b*128+jj)*600+d]);
    s = wredsum(s);
    if (lane==0) sbuf[jj]=s;
  }
  __syncthreads();
  float v = (tid<128) ? sbuf[tid] : -3.4e38f;
  red[tid]=v; __syncthreads();
  for (int s2=128;s2>0;s2>>=1){ if (tid<s2) red[tid]=fmaxf(red[tid],red[tid+s2]); __syncthreads(); }
  float mx = red[0]; __syncthreads();
  float e = (tid<128) ? expf(v-mx) : 0.f;
  red[tid]=e; __syncthreads();
  for (int s2=128;s2>0;s2>>=1){ if (tid<s2) red[tid]+=red[tid+s2]; __syncthreads(); }
  float sm = red[0]; __syncthreads();
  if (tid<128) sbuf[tid] = e/sm;
  __syncthreads();
  for (int d=tid; d<600; d+=256){
    float acc=0.f;
    for (int j=0;j<128;j++) acc += sbuf[j]*bf2f(X[(long)(b*128+j)*600+d]);
    pooled[(long)b*1200 + poff + d] = acc;
  }
}

__global__ __launch_bounds__(64) void k_final(const float* __restrict__ pooled,
                                              const ushort_t* __restrict__ fcw,
                                              const ushort_t* __restrict__ fcb,
                                              void* __restrict__ out,
                                              const ushort_t* __restrict__ probe_src){
  bool isbf = probe_is_bf16(probe_src);
  int b = blockIdx.x, lane = threadIdx.x;
  for (int p=0;p<3;p++){
    float s=0.f;
    for (int d=lane; d<1200; d+=64) s += pooled[(long)b*1200+d]*bf2f(fcw[d*3+p]);
    s = wredsum(s);
    if (lane==0){
      float r = s + bf2f(fcb[p]);
      if (isbf) ((ushort_t*)out)[b*3+p] = f2bf(r);
      else      ((float*)out)[b*3+p] = r;
    }
  }
}

// ---------------------------------------------------------------------------
extern "C" void kernel_launch(void* const* d_in, const int* in_sizes, int n_in,
                              void* d_out, int out_size, void* d_ws, size_t ws_size,
                              hipStream_t stream) {
  const int*      ti   = (const int*)d_in[0];
  const int*      ai   = (const int*)d_in[1];
  const int*      li   = (const int*)d_in[2];
  const int*      pi   = (const int*)d_in[3];
  const int*      aps  = (const int*)d_in[4];
  const ushort_t* probe = (const ushort_t*)d_in[7];

  char* w = (char*)d_ws; size_t off = 0;
  auto alloc = [&](size_t bytes)->char*{ char* p = w+off; off = (off+bytes+255)&~(size_t)255; return p; };

  int*   text_len = (int*)alloc(512);
  int*   left_len = (int*)alloc(512);
  int*   nonpad   = (int*)alloc(65536);
  float* asp_mean = (float*)alloc(153600);
  float* dn1      = (float*)alloc(65536);
  float* dn2      = (float*)alloc(65536);
  float* ymean    = (float*)alloc(65536);
  float* ysoft    = (float*)alloc(65536);
  ushort_t* wihpf = (ushort_t*)alloc(806400);
  ushort_t* wihpb = (ushort_t*)alloc(806400);
  ushort_t* whhpf = (ushort_t*)alloc(778240);   // [4][304][320]
  ushort_t* whhpb = (ushort_t*)alloc(778240);
  float* biasgf   = (float*)alloc(4800);
  float* biasgb   = (float*)alloc(4800);
  float* bqf      = (float*)alloc(2400);
  float* bkf      = (float*)alloc(2400);
  float* gc1bf    = (float*)alloc(2400);
  float* gc2bf    = (float*)alloc(2400);
  ushort_t* g1    = (ushort_t*)alloc(153600);
  ushort_t* g2    = (ushort_t*)alloc(153600);
  ushort_t* xr    = (ushort_t*)alloc(153600);
  ushort_t* xsr   = (ushort_t*)alloc(153600);
  float* pooled   = (float*)alloc(614400);
  ushort_t* adj_c  = (ushort_t*)alloc(4194304);
  ushort_t* pe_c   = (ushort_t*)alloc(2048);
  ushort_t* wihf_c = (ushort_t*)alloc(792000);
  ushort_t* wihb_c = (ushort_t*)alloc(792000);
  ushort_t* whhf_c = (ushort_t*)alloc(720000);
  ushort_t* whhb_c = (ushort_t*)alloc(720000);
  ushort_t* bihf_c = (ushort_t*)alloc(2400);
  ushort_t* bhhf_c = (ushort_t*)alloc(2400);
  ushort_t* bihb_c = (ushort_t*)alloc(2400);
  ushort_t* bhhb_c = (ushort_t*)alloc(2400);
  ushort_t* wq_c   = (ushort_t*)alloc(720000);
  ushort_t* bq_c   = (ushort_t*)alloc(1200);
  ushort_t* wk_c   = (ushort_t*)alloc(720000);
  ushort_t* bk_c   = (ushort_t*)alloc(1200);
  ushort_t* sw1_c  = (ushort_t*)alloc(3072);
  ushort_t* sb1_c  = (ushort_t*)alloc(256);
  ushort_t* sw2_c  = (ushort_t*)alloc(3072);
  ushort_t* sb2_c  = (ushort_t*)alloc(256);
  ushort_t* g1w_c  = (ushort_t*)alloc(720000);
  ushort_t* g1b_c  = (ushort_t*)alloc(1200);
  ushort_t* g2w_c  = (ushort_t*)alloc(720000);
  ushort_t* g2b_c  = (ushort_t*)alloc(1200);
  ushort_t* af1_c  = (ushort_t*)alloc(720000);
  ushort_t* af2_c  = (ushort_t*)alloc(720000);
  ushort_t* fcw_c  = (ushort_t*)alloc(7200);
  ushort_t* fcb_c  = (ushort_t*)alloc(256);
  ushort_t* embs  = (ushort_t*)alloc(11010048);
  ushort_t* textout = (ushort_t*)alloc(19660800);
  char* R = alloc(95420416);
  ushort_t* em_c    = (ushort_t*)(R);            // 18 MB; dead after k_embs
  ushort_t* gi_f    = (ushort_t*)(R);
  ushort_t* gi_b    = (ushort_t*)(R+39321600);
  ushort_t* qh      = (ushort_t*)(R);
  ushort_t* kh      = (ushort_t*)(R+20447232);
  float*    scores  = (float*)(R+40894464);
  ushort_t* adj_sem = (ushort_t*)(R+91226112);
  ushort_t* se_x    = (ushort_t*)(R+40894464);
  ushort_t* Zb      = (ushort_t*)(R+60555264);
  ushort_t* x_sem   = (ushort_t*)(R);
  ushort_t* xb      = (ushort_t*)(R+20447232);
  (void)ws_size; (void)n_in; (void)in_sizes; (void)out_size;

  // --- normalize all float inputs to bf16 (cheap per-block probe, x8 vec) ---
  {
    const int idx[27] = {7,6, 8,9,13,10,14,11,12,15,16,17,18,19,20,21,22,23,24,25,26,27,28,29,30,31,32};
    ushort_t* dl[27] = {em_c,adj_c, pe_c,wihf_c,wihb_c,whhf_c,whhb_c,bihf_c,bhhf_c,bihb_c,bhhb_c,
                        wq_c,bq_c,wk_c,bk_c,sw1_c,sb1_c,sw2_c,sb2_c,
                        g1w_c,g1b_c,g2w_c,g2b_c,af1_c,af2_c,fcw_c,fcb_c};
    const long nl[27] = {9000000L,2097152L, 900,396000,396000,360000,360000,1200,1200,1200,1200,
                         360000,600,360000,600,1536,12,1536,128,
                         360000,600,360000,600,360000,360000,3600,3};
    for (int i=0;i<27;i++){
      long nb = ((nl[i]+7)/8 + 255)/256;
      k_cvt8<<<(int)nb,256,0,stream>>>(d_in[idx[i]], dl[i], nl[i], probe);
    }
  }

  // --- prep ---
  k_lens<<<128,128,0,stream>>>(ti, li, nonpad, text_len, left_len);
  k_aspmean<<<128,128,0,stream>>>(ai, em_c, asp_mean);
  k_embs<<<16384,128,0,stream>>>(ti, pi, aps, em_c, pe_c, asp_mean, embs);
  k_padcopy<<<(1200*336+255)/256,256,0,stream>>>(wihf_c, wihpf, 1200, 330, 336);
  k_padcopy<<<(1200*336+255)/256,256,0,stream>>>(wihb_c, wihpb, 1200, 330, 336);
  k_padwhh<<<(1216*320+255)/256,256,0,stream>>>(whhf_c, whhpf);
  k_padwhh<<<(1216*320+255)/256,256,0,stream>>>(whhb_c, whhpb);
  k_biassum<<<(1200+255)/256,256,0,stream>>>(bihf_c, bhhf_c, biasgf, 1200);
  k_biassum<<<(1200+255)/256,256,0,stream>>>(bihb_c, bhhb_c, biasgb, 1200);
  k_biascvt<<<3,256,0,stream>>>(bq_c, bqf, 600);
  k_biascvt<<<3,256,0,stream>>>(bk_c, bkf, 600);
  k_biascvt<<<3,256,0,stream>>>(g1b_c, gc1bf, 600);
  k_biascvt<<<3,256,0,stream>>>(g2b_c, gc2bf, 600);

  // --- input projections (embs @ Wih^T + bias) ---
  gemm_k<1,1><<<dim3(128,10,1),256,0,stream>>>(16384,1200,336, embs,336,0, wihpf,336,0,
        nullptr, gi_f,1200,0, biasgf,0,nullptr,nullptr);
  gemm_k<1,1><<<dim3(128,10,1),256,0,stream>>>(16384,1200,336, embs,336,0, wihpb,336,0,
        nullptr, gi_b,1200,0, biasgb,0,nullptr,nullptr);

  // --- BiLSTM: one launch, communication-free (batch-partitioned) ---
  lstm_block_k<<<16,256,0,stream>>>(gi_f, gi_b, whhpf, whhpb, textout, text_len);

  // --- q/k projections, head-scattered (dk padded 100->104) ---
  hipMemsetAsync(qh, 0, 20447232, stream);
  hipMemsetAsync(kh, 0, 20447232, stream);
  gemm_k<1,2><<<dim3(128,5,1),256,0,stream>>>(16384,600,600, textout,600,0, wq_c,600,0,
        nullptr, qh,0,0, bqf,0,nullptr,nullptr);
  gemm_k<1,2><<<dim3(128,5,1),256,0,stream>>>(16384,600,600, textout,600,0, wk_c,600,0,
        nullptr, kh,0,0, bkf,0,nullptr,nullptr);

  // --- attention scores + mask ---
  gemm_k<1,3><<<dim3(1,1,768),256,0,stream>>>(128,128,104, qh,104,13312, kh,104,13312,
        scores, nullptr, 128, 16384, nullptr,0,nullptr, nonpad);

  // --- entmax15 (in place) ---
  k_entmax<<<98304,64,0,stream>>>(scores);

  // --- adjacency: head-mean + eye + valid; degree norms ---
  k_adjsem<<<(2097152+255)/256,256,0,stream>>>(scores, nonpad, adj_sem);
  k_dn<<<16384,64,0,stream>>>(adj_sem, dn1);
  k_dn<<<16384,64,0,stream>>>(adj_c, dn2);

  // --- SE #1 + GCN #1 (norm folded: Z = D (A (D * se * X))) ---
  k_mean<<<16384,64,0,stream>>>(textout, ymean);
  k_senet<<<128,128,0,stream>>>(ymean, sw1_c,sb1_c,sw2_c,sb2_c, nonpad, ysoft);
  k_scale2<<<(9830400+255)/256,256,0,stream>>>(textout, ysoft, dn1, se_x);
  gemm_k<0,1><<<dim3(1,5,128),256,0,stream>>>(128,600,128, adj_sem,128,16384, se_x,600,76800,
        nullptr, Zb,600,76800, nullptr,0, dn1, nullptr);
  gemm_k<0,1><<<dim3(128,5,1),256,0,stream>>>(16384,600,600, Zb,600,0, g1w_c,600,0,
        nullptr, x_sem,600,0, gc1bf,1,nullptr,nullptr);

  // --- SE #2 + GCN #2 (uses input adj) ---
  k_mean<<<16384,64,0,stream>>>(x_sem, ymean);
  k_senet<<<128,128,0,stream>>>(ymean, sw1_c,sb1_c,sw2_c,sb2_c, nonpad, ysoft);
  k_scale2<<<(9830400+255)/256,256,0,stream>>>(x_sem, ysoft, dn2, se_x);
  gemm_k<0,1><<<dim3(1,5,128),256,0,stream>>>(128,600,128, adj_c,128,16384, se_x,600,76800,
        nullptr, Zb,600,76800, nullptr,0, dn2, nullptr);
  gemm_k<0,1><<<dim3(128,5,1),256,0,stream>>>(16384,600,600, Zb,600,0, g2w_c,600,0,
        nullptr, xb,600,0, gc2bf,1,nullptr,nullptr);

  // --- biaffine pooling (only row left_len[b] of A1/A2 is ever used) ---
  k_gather<<<128,128,0,stream>>>(xb, left_len, xr);
  k_gather<<<128,128,0,stream>>>(x_sem, left_len, xsr);
  gemm_k<0,1><<<dim3(1,5,1),256,0,stream>>>(128,600,600, xr,600,0, af1_c,600,0,
        nullptr, g1,600,0, nullptr,0,nullptr,nullptr);
  gemm_k<0,1><<<dim3(1,5,1),256,0,stream>>>(128,600,600, xsr,600,0, af2_c,600,0,
        nullptr, g2,600,0, nullptr,0,nullptr,nullptr);
  k_pool<<<128,256,0,stream>>>(g1, x_sem, pooled, 0);
  k_pool<<<128,256,0,stream>>>(g2, xb, pooled, 600);

  // --- final FC (dtype-adaptive output) ---
  k_final<<<128,64,0,stream>>>(pooled, fcw_c, fcb_c, d_out, probe);
}

// Round 9
// 3935.812 us; speedup vs baseline: 2.4826x; 1.3195x over previous
//
#include <hip/hip_runtime.h>

typedef unsigned short ushort_t;
typedef unsigned int   uint_t;
typedef __attribute__((ext_vector_type(8))) short short8;
typedef __attribute__((ext_vector_type(4))) float floatx4;

#define NEGV -1000000000.0f

__device__ __forceinline__ float bf2f(ushort_t h){ return __uint_as_float(((uint_t)h)<<16); }
__device__ __forceinline__ ushort_t f2bf(float f){
  uint_t u = __float_as_uint(f);
  uint_t r = u + 0x7fffu + ((u>>16)&1u);
  return (ushort_t)(r>>16);
}
__device__ __forceinline__ float wredsum(float v){ for(int o=32;o;o>>=1) v += __shfl_xor(v,o); return v; }
__device__ __forceinline__ float wredmax(float v){ for(int o=32;o;o>>=1) v = fmaxf(v,__shfl_xor(v,o)); return v; }
__device__ __forceinline__ int   wredsumi(int v){ for(int o=32;o;o>>=1) v += __shfl_xor(v,o); return v; }

// ---------------------------------------------------------------------------
// dtype-adaptive conversion, vectorized x8. Probe once per block in wave 0.
// ---------------------------------------------------------------------------
__global__ void k_cvt8(const void* __restrict__ src, ushort_t* __restrict__ dst,
                       long n, const ushort_t* __restrict__ probe_src){
  __shared__ int sflag;
  if (threadIdx.x < 64){
    ushort_t u = probe_src[2*threadIdx.x];
    int e = (u>>7)&0xFF;
    int c = (e>=100 && e<=140) ? 1 : 0;
    c = wredsumi(c);
    if (threadIdx.x==0) sflag = (c>32) ? 1 : 0;
  }
  __syncthreads();
  bool isbf = (sflag!=0);
  long base = (blockIdx.x*256L + threadIdx.x)*8;
  if (base>=n) return;
  if (isbf){
    if (base+8<=n) *(uint4*)(dst+base) = *(const uint4*)((const ushort_t*)src+base);
    else for (long i=base;i<n;i++) dst[i]=((const ushort_t*)src)[i];
  } else {
    const float* s = (const float*)src;
    if (base+8<=n){
      float4 v0 = *(const float4*)(s+base);
      float4 v1 = *(const float4*)(s+base+4);
      ushort_t o[8] = {f2bf(v0.x),f2bf(v0.y),f2bf(v0.z),f2bf(v0.w),
                       f2bf(v1.x),f2bf(v1.y),f2bf(v1.z),f2bf(v1.w)};
      *(uint4*)(dst+base) = *(uint4*)o;
    } else {
      for (long i=base;i<n;i++) dst[i]=f2bf(s[i]);
    }
  }
}

__device__ __forceinline__ bool probe_is_bf16(const ushort_t* probe_src){
  int c=0;
  #pragma unroll 1
  for (int i=0;i<64;i++){
    ushort_t u = probe_src[2*i];
    int e = (u>>7)&0xFF;
    c += (e>=100 && e<=140) ? 1 : 0;
  }
  return c>32;
}

// ---------------------------------------------------------------------------
// small prep kernels
// ---------------------------------------------------------------------------
__global__ void k_lens(const int* __restrict__ ti, const int* __restrict__ li,
                       int* __restrict__ nonpad, int* __restrict__ text_len,
                       int* __restrict__ left_len){
  int b = blockIdx.x, t = threadIdx.x;
  nonpad[b*128+t] = (ti[b*128+t]!=0) ? 1 : 0;
  if (t==0){
    int c=0; for (int k2=0;k2<128;k2++) c += (ti[b*128+k2]!=0);
    text_len[b]=c;
    int l=0; for (int k2=0;k2<24;k2++) l += (li[b*24+k2]!=0);
    left_len[b]=l;
  }
}

__global__ void k_aspmean(const int* __restrict__ ai, const ushort_t* __restrict__ em,
                          float* __restrict__ asp_mean){
  int b = blockIdx.x;
  int idxs[5]; int cnt=0;
  for (int a=0;a<5;a++){ int ix=ai[b*5+a]; idxs[a]=ix; cnt += (ix!=0); }
  float inv = 1.0f/(float)cnt;
  for (int d=threadIdx.x; d<300; d+=128){
    float s=0.f;
    for (int a=0;a<5;a++) if (idxs[a]) s += bf2f(em[(long)idxs[a]*300+d]);
    asp_mean[b*300+d] = s*inv;
  }
}

__global__ void k_embs(const int* __restrict__ ti, const int* __restrict__ pi,
                       const int* __restrict__ asp_post,
                       const ushort_t* __restrict__ em, const ushort_t* __restrict__ pe,
                       const float* __restrict__ asp_mean, ushort_t* __restrict__ embs){
  int blk = blockIdx.x;
  int b = blk>>7, t = blk&127;
  int ap = asp_post[b];
  int tix = ti[b*128+t];
  int pix = pi[b*128+t];
  for (int col=threadIdx.x; col<336; col+=128){
    ushort_t v;
    if (col<300) v = (t==ap) ? f2bf(asp_mean[b*300+col]) : em[(long)tix*300+col];
    else if (col<330) v = pe[pix*30 + (col-300)];
    else v = 0;
    embs[(long)(b*128+t)*336 + col] = v;
  }
}

__global__ void k_padcopy(const ushort_t* __restrict__ src, ushort_t* __restrict__ dst,
                          int rows, int sk, int dk){
  int i = blockIdx.x*blockDim.x + threadIdx.x;
  int n = rows*dk;
  if (i<n){
    int r = i/dk, c2 = i - r*dk;
    dst[i] = (c2<sk) ? src[r*sk+c2] : 0;
  }
}

// Whh repack: dst[4][304][320], per-gate rows padded 300->304, K 300->320, zeros.
__global__ void k_padwhh(const ushort_t* __restrict__ src, ushort_t* __restrict__ dst){
  int i = blockIdx.x*blockDim.x + threadIdx.x;
  if (i >= 1216*320) return;
  int r = i/320, k = i - r*320;
  int gate = r/304, jj = r - gate*304;
  ushort_t v = 0;
  if (jj<300 && k<300) v = src[(long)(gate*300+jj)*300 + k];
  dst[i] = v;
}

__global__ void k_biassum(const ushort_t* __restrict__ a, const ushort_t* __restrict__ b,
                          float* __restrict__ dst, int n){
  int i = blockIdx.x*blockDim.x + threadIdx.x;
  if (i<n) dst[i] = bf2f(a[i]) + bf2f(b[i]);
}
__global__ void k_biascvt(const ushort_t* __restrict__ a, float* __restrict__ dst, int n){
  int i = blockIdx.x*blockDim.x + threadIdx.x;
  if (i<n) dst[i] = bf2f(a[i]);
}

// ---------------------------------------------------------------------------
// generic bf16 MFMA GEMM: 128x128 tile, 4 waves (2x2), each 64x64 via 4x4
// frags of 16x16x32.  TB=1: C = A * B^T.  TB=0: C = A * B.
// MODE 1: bf16 store (opt bias/relu/rowscale)
// MODE 2: qk head-scatter bf16 store (bias), T=128, dk=100->104
// MODE 3: f32 store, *0.1 and nonpad column mask (attention scores)
// ---------------------------------------------------------------------------
template<int TB, int MODE>
__global__ __launch_bounds__(256) void gemm_k(
    int M, int N, int K,
    const ushort_t* __restrict__ A, long lda, long sAz,
    const ushort_t* __restrict__ B, long ldb, long sBz,
    float* __restrict__ Cf, ushort_t* __restrict__ Cb, long ldc, long sCz,
    const float* __restrict__ bias, int relu,
    const float* __restrict__ rowscale,
    const int* __restrict__ nonpad)
{
  __shared__ ushort_t As[128*40];
  __shared__ ushort_t Bs[128*40];
  const int tid = threadIdx.x;
  const int m0 = blockIdx.x*128, n0 = blockIdx.y*128;
  const int z = blockIdx.z;
  const ushort_t* Ap = A + (long)z*sAz;
  const ushort_t* Bp = B + (long)z*sBz;
  floatx4 acc[4][4];
  #pragma unroll
  for (int i=0;i<4;i++)
    #pragma unroll
    for (int j=0;j<4;j++){ acc[i][j][0]=0.f; acc[i][j][1]=0.f; acc[i][j][2]=0.f; acc[i][j][3]=0.f; }
  const int w = tid>>6, wm = w&1, wn = w>>1;
  const int lane = tid&63, lr = lane&15, lq = lane>>4;

  for (int k0=0;k0<K;k0+=32){
    #pragma unroll
    for (int c2=0;c2<2;c2++){
      int ch = tid + 256*c2;
      int row = ch>>2, kc = (ch&3)*8;
      int gr = m0+row, gk = k0+kc;
      uint4 v{};
      if (gr<M && gk<K) v = *(const uint4*)(Ap + (long)gr*lda + gk);
      *(uint4*)(&As[row*40+kc]) = v;
    }
    if (TB){
      #pragma unroll
      for (int c2=0;c2<2;c2++){
        int ch = tid + 256*c2;
        int row = ch>>2, kc = (ch&3)*8;
        int gn = n0+row, gk = k0+kc;
        uint4 v{};
        if (gn<N && gk<K) v = *(const uint4*)(Bp + (long)gn*ldb + gk);
        int sw = kc ^ (((row>>3)&3)<<3);
        *(uint4*)(&Bs[row*40+sw]) = v;
      }
    } else {
      #pragma unroll
      for (int c2=0;c2<2;c2++){
        int ch = tid + 256*c2;
        int kk = ch>>4, nc = (ch&15)*8;
        int gk = k0+kk, gn = n0+nc;
        uint4 v{};
        if (gk<K && gn<N) v = *(const uint4*)(Bp + (long)gk*ldb + gn);
        uint_t wsv[4] = {v.x, v.y, v.z, v.w};
        #pragma unroll
        for (int e=0;e<8;e++){
          ushort_t hv = (e&1) ? (ushort_t)(wsv[e>>1]>>16) : (ushort_t)(wsv[e>>1]&0xffffu);
          int n = nc+e;
          int sw = kk ^ (((n>>3)&3)<<3);
          Bs[n*40+sw] = hv;
        }
      }
    }
    __syncthreads();
    short8 af[4], bfv[4];
    #pragma unroll
    for (int i=0;i<4;i++) af[i] = *(const short8*)(&As[(wm*64+i*16+lr)*40 + lq*8]);
    #pragma unroll
    for (int j=0;j<4;j++){
      int n = wn*64+j*16+lr;
      int sw = (lq*8) ^ (((n>>3)&3)<<3);
      bfv[j] = *(const short8*)(&Bs[n*40+sw]);
    }
    #pragma unroll
    for (int i=0;i<4;i++)
      #pragma unroll
      for (int j=0;j<4;j++)
        acc[i][j] = __builtin_amdgcn_mfma_f32_16x16x32_bf16(af[i], bfv[j], acc[i][j], 0,0,0);
    __syncthreads();
  }

  #pragma unroll
  for (int i=0;i<4;i++){
    #pragma unroll
    for (int j=0;j<4;j++){
      #pragma unroll
      for (int r=0;r<4;r++){
        int row = m0 + wm*64 + i*16 + lq*4 + r;
        int col = n0 + wn*64 + j*16 + lr;
        if (row<M && col<N){
          float v = acc[i][j][r];
          if (rowscale) v *= rowscale[(long)z*M + row];
          if (bias) v += bias[col];
          if (relu && v<0.f) v = 0.f;
          if (MODE==1){
            Cb[(long)z*sCz + (long)row*ldc + col] = f2bf(v);
          } else if (MODE==2){
            int b = row>>7, t = row&127;
            int h = col/100, d = col - h*100;
            Cb[ ((long)((b*6+h)*128+t))*104 + d ] = f2bf(v);
          } else if (MODE==3){
            v *= 0.1f;
            if (!nonpad[(z/6)*128 + col]) v = NEGV;
            Cf[(long)z*sCz + (long)row*ldc + col] = v;
          }
        }
      }
    }
  }
}

// ---------------------------------------------------------------------------
// Communication-free BiLSTM, latency-provisioned: grid 128 = 64 batch-pairs
// x 2 dirs; block 256 (4 waves). Each block owns 2 batches for all 128
// steps; h in LDS, c in registers. Wave w computes gate w: 19 j-tiles x
// 10 K-tiles of 16x16x32 MFMA, A (Whh) loaded directly from L2-resident
// global with an explicit nt-level double buffer; B (h) from LDS (2 valid
// cols). No atomics, no grid barrier, no cross-block state.
// whh layout: [4][304][320].
// ---------------------------------------------------------------------------
__global__ __launch_bounds__(256) void lstm_block_k(
    const ushort_t* __restrict__ gi_f, const ushort_t* __restrict__ gi_b,
    const ushort_t* __restrict__ whh_f, const ushort_t* __restrict__ whh_b,
    ushort_t* __restrict__ text_out, const int* __restrict__ text_len)
{
  const int bx = blockIdx.x;
  const int dir = bx>>6, bg = bx&63;
  const ushort_t* gi  = dir ? gi_b  : gi_f;
  const ushort_t* whh = dir ? whh_b : whh_f;

  __shared__ __align__(16) ushort_t h_lds[2][328];
  __shared__ __align__(16) float    g_lds[4][2][304];
  __shared__ int s_tlen[2];

  const int tid = threadIdx.x;
  const int w = tid>>6, lane = tid&63, lr = lane&15, lq = lane>>4;

  for (int i=tid; i<2*328; i+=256) ((ushort_t*)h_lds)[i] = 0;
  if (tid<2) s_tlen[tid] = text_len[bg*2+tid];
  float c_reg[3]; c_reg[0]=0.f; c_reg[1]=0.f; c_reg[2]=0.f;
  __syncthreads();

  const ushort_t* wbase = whh + (long)w*304*320;
  const ushort_t* arow0 = wbase + (long)lr*320 + lq*8;

  for (int s=0; s<128; s++){
    const int t = dir ? (127-s) : s;

    // gi register prefetch (independent; overlaps MFMA phase)
    ushort_t gp[3][4];
    #pragma unroll
    for (int it=0; it<3; it++){
      int item = tid + it*256;
      if (item<600){
        int b = item/300, j = item - b*300;
        long gb = ((long)((bg*2+b)*128 + t))*1200 + j;
        gp[it][0] = gi[gb];
        gp[it][1] = gi[gb+300];
        gp[it][2] = gi[gb+600];
        gp[it][3] = gi[gb+900];
      }
    }

    // B fragments: h rows (cols 0..1 valid, rest zero)
    short8 bfv[10];
    #pragma unroll
    for (int kt=0; kt<10; kt++){
      short8 z = {0,0,0,0,0,0,0,0};
      bfv[kt] = (lr<2) ? *(const short8*)(&h_lds[lr][kt*32 + lq*8]) : z;
    }

    // MFMA over 19 j-tiles, double-buffered A loads
    short8 a0[10], a1[10];
    #pragma unroll
    for (int kt=0; kt<10; kt++) a0[kt] = *(const short8*)(arow0 + kt*32);
    #pragma unroll 1
    for (int nt=0; nt<19; nt++){
      if (nt<18){
        const ushort_t* an = wbase + (long)((nt+1)*16 + lr)*320 + lq*8;
        #pragma unroll
        for (int kt=0; kt<10; kt++) a1[kt] = *(const short8*)(an + kt*32);
      }
      floatx4 acc; acc[0]=0.f; acc[1]=0.f; acc[2]=0.f; acc[3]=0.f;
      #pragma unroll
      for (int kt=0; kt<10; kt++)
        acc = __builtin_amdgcn_mfma_f32_16x16x32_bf16(a0[kt], bfv[kt], acc, 0,0,0);
      if (lr<2) *(float4*)(&g_lds[w][lr][nt*16 + lq*4]) = *(float4*)&acc;
      #pragma unroll
      for (int kt=0; kt<10; kt++) a0[kt] = a1[kt];
    }
    __syncthreads();

    // epilogue: gates, c (regs) / h (LDS) update, text_out store
    #pragma unroll
    for (int it=0; it<3; it++){
      int item = tid + it*256;
      if (item<600){
        int b = item/300, j = item - b*300;
        float g_i = g_lds[0][b][j] + bf2f(gp[it][0]);
        float g_f = g_lds[1][b][j] + bf2f(gp[it][1]);
        float g_g = g_lds[2][b][j] + bf2f(gp[it][2]);
        float g_o = g_lds[3][b][j] + bf2f(gp[it][3]);
        float ig = 1.f/(1.f+expf(-g_i));
        float fg = 1.f/(1.f+expf(-g_f));
        float gg = tanhf(g_g);
        float og = 1.f/(1.f+expf(-g_o));
        float cn = fg*c_reg[it] + ig*gg;
        float hn = og*tanhf(cn);
        int m = (t < s_tlen[b]) ? 1 : 0;
        if (m) c_reg[it] = cn;
        float hold = bf2f(h_lds[b][j]);
        float hv = m ? hn : hold;
        h_lds[b][j] = f2bf(hv);
        text_out[((long)((bg*2+b)*128+t))*600 + dir*300 + j] = f2bf(m ? hn : 0.f);
      }
    }
    __syncthreads();
  }
}

// ---------------------------------------------------------------------------
// entmax15 over rows of 128 (in-place on f32 scores). 1 wave per row.
// ---------------------------------------------------------------------------
__global__ __launch_bounds__(64) void k_entmax(float* __restrict__ p){
  long row = blockIdx.x;
  float* base = p + row*128;
  __shared__ float xo[128], xs[128], c1[128], c2[128];
  int t = threadIdx.x;
  float a = base[t]*0.5f, b = base[t+64]*0.5f;
  float m = wredmax(fmaxf(a,b));
  a -= m; b -= m;
  xo[t]=a; xo[t+64]=b; xs[t]=a; xs[t+64]=b;
  __syncthreads();
  for (int k2=2;k2<=128;k2<<=1){
    for (int j=k2>>1;j>0;j>>=1){
      int i = ((t & ~(j-1))<<1) | (t & (j-1));
      int ixj = i | j;
      float vi = xs[i], vj = xs[ixj];
      bool blk = (i & k2)==0;
      bool sw = blk ? (vi < vj) : (vi > vj);
      __syncthreads();
      if (sw){ xs[i]=vj; xs[ixj]=vi; }
      __syncthreads();
    }
  }
  c1[t]=xs[t];       c2[t]=xs[t]*xs[t];
  c1[t+64]=xs[t+64]; c2[t+64]=xs[t+64]*xs[t+64];
  __syncthreads();
  for (int d=1; d<128; d<<=1){
    float a1 = (t>=d)     ? c1[t-d]    : 0.f;
    float a2 = (t>=d)     ? c2[t-d]    : 0.f;
    float b1 = (t+64>=d)  ? c1[t+64-d] : 0.f;
    float b2 = (t+64>=d)  ? c2[t+64-d] : 0.f;
    float x1=c1[t], y1=c2[t], x2=c1[t+64], y2=c2[t+64];
    __syncthreads();
    c1[t]=x1+a1; c2[t]=y1+a2; c1[t+64]=x2+b1; c2[t+64]=y2+b2;
    __syncthreads();
  }
  float tau_a, tau_b; int cnt=0;
  {
    float rho = (float)(t+1);
    float mean = c1[t]/rho, msq = c2[t]/rho;
    float ss = rho*(msq-mean*mean);
    float delta = (1.f-ss)/rho;
    tau_a = mean - sqrtf(fmaxf(delta,0.f));
    cnt += (tau_a <= xs[t]) ? 1 : 0;
  }
  {
    float rho = (float)(t+65);
    float mean = c1[t+64]/rho, msq = c2[t+64]/rho;
    float ss = rho*(msq-mean*mean);
    float delta = (1.f-ss)/rho;
    tau_b = mean - sqrtf(fmaxf(delta,0.f));
    cnt += (tau_b <= xs[t+64]) ? 1 : 0;
  }
  __syncthreads();
  c1[t]=tau_a; c1[t+64]=tau_b;
  __syncthreads();
  int support = wredsumi(cnt);
  support = (support<1) ? 1 : ((support>128) ? 128 : support);
  float tau_star = c1[support-1];
  float oa = fmaxf(xo[t]-tau_star, 0.f);
  float ob = fmaxf(xo[t+64]-tau_star, 0.f);
  base[t] = oa*oa; base[t+64] = ob*ob;
}

// ---------------------------------------------------------------------------
__global__ void k_adjsem(const float* __restrict__ p, const int* __restrict__ nonpad,
                         ushort_t* __restrict__ adj_sem){
  int idx = blockIdx.x*blockDim.x + threadIdx.x;
  if (idx >= 128*128*128) return;
  int b = idx>>14, rem = idx&16383, i = rem>>7, j = rem&127;
  float s = 0.f;
  for (int h=0;h<6;h++) s += p[(long)b*98304 + h*16384 + i*128 + j];
  float v = s/6.0f;
  if (i==j) v = 1.0f;
  if (!nonpad[b*128+i]) v = 0.f;
  adj_sem[idx] = f2bf(v);
}

__global__ __launch_bounds__(64) void k_dn(const ushort_t* __restrict__ src, float* __restrict__ dnv){
  long row = blockIdx.x;
  int l = threadIdx.x;
  float s = bf2f(src[row*128+l]) + bf2f(src[row*128+l+64]);
  s = wredsum(s);
  if (l==0) dnv[row] = 1.0f/sqrtf(s+1.0f);
}

__global__ __launch_bounds__(64) void k_mean(const ushort_t* __restrict__ X, float* __restrict__ ymean){
  long row = blockIdx.x;
  float s=0.f;
  for (int d=threadIdx.x; d<600; d+=64) s += bf2f(X[row*600+d]);
  s = wredsum(s);
  if (threadIdx.x==0) ymean[row] = s/600.0f;
}

__global__ void k_senet(const float* __restrict__ ymean,
                        const ushort_t* __restrict__ w1, const ushort_t* __restrict__ b1,
                        const ushort_t* __restrict__ w2, const ushort_t* __restrict__ b2,
                        const int* __restrict__ nonpad, float* __restrict__ ysoft){
  int b = blockIdx.x, t = threadIdx.x;
  __shared__ float yv[128], z1[12], red[128];
  yv[t] = ymean[b*128+t];
  __syncthreads();
  if (t<12){
    float s = bf2f(b1[t]);
    for (int k2=0;k2<128;k2++) s += yv[k2]*bf2f(w1[t*128+k2]);
    z1[t] = fmaxf(s,0.f);
  }
  __syncthreads();
  float v = bf2f(b2[t]);
  for (int r=0;r<12;r++) v += z1[r]*bf2f(w2[t*12+r]);
  if (!nonpad[b*128+t]) v += NEGV;
  red[t]=v; __syncthreads();
  for (int s2=64;s2>0;s2>>=1){ if (t<s2) red[t]=fmaxf(red[t],red[t+s2]); __syncthreads(); }
  float mx = red[0]; __syncthreads();
  float e = expf(v-mx);
  red[t]=e; __syncthreads();
  for (int s2=64;s2>0;s2>>=1){ if (t<s2) red[t]+=red[t+s2]; __syncthreads(); }
  float sm = red[0];
  ysoft[b*128+t] = e/sm;
}

__global__ void k_scale2(const ushort_t* __restrict__ X, const float* __restrict__ ysoft,
                         const float* __restrict__ dnv, ushort_t* __restrict__ out){
  int i = blockIdx.x*blockDim.x + threadIdx.x;
  if (i >= 128*128*600) return;
  int row = i/600;
  out[i] = f2bf(bf2f(X[i])*ysoft[row]*dnv[row]);
}

__global__ void k_gather(const ushort_t* __restrict__ X, const int* __restrict__ left_len,
                         ushort_t* __restrict__ dst){
  int b = blockIdx.x;
  int lb = left_len[b];
  for (int d=threadIdx.x; d<600; d+=128)
    dst[b*600+d] = X[(long)(b*128+lb)*600+d];
}

__global__ __launch_bounds__(256) void k_pool(const ushort_t* __restrict__ g,
                                              const ushort_t* __restrict__ X,
                                              float* __restrict__ pooled, int poff){
  int b = blockIdx.x, tid = threadIdx.x;
  __shared__ float gs[600], sbuf[128], red[256];
  for (int d=tid; d<600; d+=256) gs[d] = bf2f(g[b*600+d]);
  __syncthreads();
  int wv = tid>>6, lane = tid&63;
  for (int jj=wv; jj<128; jj+=4){
    float s=0.f;
    for (int d=lane; d<600; d+=64) s += gs[d]*bf2f(X[(long)(b*128+jj)*600+d]);
    s = wredsum(s);
    if (lane==0) sbuf[jj]=s;
  }
  __syncthreads();
  float v = (tid<128) ? sbuf[tid] : -3.4e38f;
  red[tid]=v; __syncthreads();
  for (int s2=128;s2>0;s2>>=1){ if (tid<s2) red[tid]=fmaxf(red[tid],red[tid+s2]); __syncthreads(); }
  float mx = red[0]; __syncthreads();
  float e = (tid<128) ? expf(v-mx) : 0.f;
  red[tid]=e; __syncthreads();
  for (int s2=128;s2>0;s2>>=1){ if (tid<s2) red[tid]+=red[tid+s2]; __syncthreads(); }
  float sm = red[0]; __syncthreads();
  if (tid<128) sbuf[tid] = e/sm;
  __syncthreads();
  for (int d=tid; d<600; d+=256){
    float acc=0.f;
    for (int j=0;j<128;j++) acc += sbuf[j]*bf2f(X[(long)(b*128+j)*600+d]);
    pooled[(long)b*1200 + poff + d] = acc;
  }
}

__global__ __launch_bounds__(64) void k_final(const float* __restrict__ pooled,
                                              const ushort_t* __restrict__ fcw,
                                              const ushort_t* __restrict__ fcb,
                                              void* __restrict__ out,
                                              const ushort_t* __restrict__ probe_src){
  bool isbf = probe_is_bf16(probe_src);
  int b = blockIdx.x, lane = threadIdx.x;
  for (int p=0;p<3;p++){
    float s=0.f;
    for (int d=lane; d<1200; d+=64) s += pooled[(long)b*1200+d]*bf2f(fcw[d*3+p]);
    s = wredsum(s);
    if (lane==0){
      float r = s + bf2f(fcb[p]);
      if (isbf) ((ushort_t*)out)[b*3+p] = f2bf(r);
      else      ((float*)out)[b*3+p] = r;
    }
  }
}

// ---------------------------------------------------------------------------
extern "C" void kernel_launch(void* const* d_in, const int* in_sizes, int n_in,
                              void* d_out, int out_size, void* d_ws, size_t ws_size,
                              hipStream_t stream) {
  const int*      ti   = (const int*)d_in[0];
  const int*      ai   = (const int*)d_in[1];
  const int*      li   = (const int*)d_in[2];
  const int*      pi   = (const int*)d_in[3];
  const int*      aps  = (const int*)d_in[4];
  const ushort_t* probe = (const ushort_t*)d_in[7];

  char* w = (char*)d_ws; size_t off = 0;
  auto alloc = [&](size_t bytes)->char*{ char* p = w+off; off = (off+bytes+255)&~(size_t)255; return p; };

  int*   text_len = (int*)alloc(512);
  int*   left_len = (int*)alloc(512);
  int*   nonpad   = (int*)alloc(65536);
  float* asp_mean = (float*)alloc(153600);
  float* dn1      = (float*)alloc(65536);
  float* dn2      = (float*)alloc(65536);
  float* ymean    = (float*)alloc(65536);
  float* ysoft    = (float*)alloc(65536);
  ushort_t* wihpf = (ushort_t*)alloc(806400);
  ushort_t* wihpb = (ushort_t*)alloc(806400);
  ushort_t* whhpf = (ushort_t*)alloc(778240);   // [4][304][320]
  ushort_t* whhpb = (ushort_t*)alloc(778240);
  float* biasgf   = (float*)alloc(4800);
  float* biasgb   = (float*)alloc(4800);
  float* bqf      = (float*)alloc(2400);
  float* bkf      = (float*)alloc(2400);
  float* gc1bf    = (float*)alloc(2400);
  float* gc2bf    = (float*)alloc(2400);
  ushort_t* g1    = (ushort_t*)alloc(153600);
  ushort_t* g2    = (ushort_t*)alloc(153600);
  ushort_t* xr    = (ushort_t*)alloc(153600);
  ushort_t* xsr   = (ushort_t*)alloc(153600);
  float* pooled   = (float*)alloc(614400);
  ushort_t* adj_c  = (ushort_t*)alloc(4194304);
  ushort_t* pe_c   = (ushort_t*)alloc(2048);
  ushort_t* wihf_c = (ushort_t*)alloc(792000);
  ushort_t* wihb_c = (ushort_t*)alloc(792000);
  ushort_t* whhf_c = (ushort_t*)alloc(720000);
  ushort_t* whhb_c = (ushort_t*)alloc(720000);
  ushort_t* bihf_c = (ushort_t*)alloc(2400);
  ushort_t* bhhf_c = (ushort_t*)alloc(2400);
  ushort_t* bihb_c = (ushort_t*)alloc(2400);
  ushort_t* bhhb_c = (ushort_t*)alloc(2400);
  ushort_t* wq_c   = (ushort_t*)alloc(720000);
  ushort_t* bq_c   = (ushort_t*)alloc(1200);
  ushort_t* wk_c   = (ushort_t*)alloc(720000);
  ushort_t* bk_c   = (ushort_t*)alloc(1200);
  ushort_t* sw1_c  = (ushort_t*)alloc(3072);
  ushort_t* sb1_c  = (ushort_t*)alloc(256);
  ushort_t* sw2_c  = (ushort_t*)alloc(3072);
  ushort_t* sb2_c  = (ushort_t*)alloc(256);
  ushort_t* g1w_c  = (ushort_t*)alloc(720000);
  ushort_t* g1b_c  = (ushort_t*)alloc(1200);
  ushort_t* g2w_c  = (ushort_t*)alloc(720000);
  ushort_t* g2b_c  = (ushort_t*)alloc(1200);
  ushort_t* af1_c  = (ushort_t*)alloc(720000);
  ushort_t* af2_c  = (ushort_t*)alloc(720000);
  ushort_t* fcw_c  = (ushort_t*)alloc(7200);
  ushort_t* fcb_c  = (ushort_t*)alloc(256);
  ushort_t* embs  = (ushort_t*)alloc(11010048);
  ushort_t* textout = (ushort_t*)alloc(19660800);
  char* R = alloc(95420416);
  ushort_t* em_c    = (ushort_t*)(R);            // 18 MB; dead after k_embs
  ushort_t* gi_f    = (ushort_t*)(R);
  ushort_t* gi_b    = (ushort_t*)(R+39321600);
  ushort_t* qh      = (ushort_t*)(R);
  ushort_t* kh      = (ushort_t*)(R+20447232);
  float*    scores  = (float*)(R+40894464);
  ushort_t* adj_sem = (ushort_t*)(R+91226112);
  ushort_t* se_x    = (ushort_t*)(R+40894464);
  ushort_t* Zb      = (ushort_t*)(R+60555264);
  ushort_t* x_sem   = (ushort_t*)(R);
  ushort_t* xb      = (ushort_t*)(R+20447232);
  (void)ws_size; (void)n_in; (void)in_sizes; (void)out_size;

  // --- normalize all float inputs to bf16 (cheap per-block probe, x8 vec) ---
  {
    const int idx[27] = {7,6, 8,9,13,10,14,11,12,15,16,17,18,19,20,21,22,23,24,25,26,27,28,29,30,31,32};
    ushort_t* dl[27] = {em_c,adj_c, pe_c,wihf_c,wihb_c,whhf_c,whhb_c,bihf_c,bhhf_c,bihb_c,bhhb_c,
                        wq_c,bq_c,wk_c,bk_c,sw1_c,sb1_c,sw2_c,sb2_c,
                        g1w_c,g1b_c,g2w_c,g2b_c,af1_c,af2_c,fcw_c,fcb_c};
    const long nl[27] = {9000000L,2097152L, 900,396000,396000,360000,360000,1200,1200,1200,1200,
                         360000,600,360000,600,1536,12,1536,128,
                         360000,600,360000,600,360000,360000,3600,3};
    for (int i=0;i<27;i++){
      long nb = ((nl[i]+7)/8 + 255)/256;
      k_cvt8<<<(int)nb,256,0,stream>>>(d_in[idx[i]], dl[i], nl[i], probe);
    }
  }

  // --- prep ---
  k_lens<<<128,128,0,stream>>>(ti, li, nonpad, text_len, left_len);
  k_aspmean<<<128,128,0,stream>>>(ai, em_c, asp_mean);
  k_embs<<<16384,128,0,stream>>>(ti, pi, aps, em_c, pe_c, asp_mean, embs);
  k_padcopy<<<(1200*336+255)/256,256,0,stream>>>(wihf_c, wihpf, 1200, 330, 336);
  k_padcopy<<<(1200*336+255)/256,256,0,stream>>>(wihb_c, wihpb, 1200, 330, 336);
  k_padwhh<<<(1216*320+255)/256,256,0,stream>>>(whhf_c, whhpf);
  k_padwhh<<<(1216*320+255)/256,256,0,stream>>>(whhb_c, whhpb);
  k_biassum<<<(1200+255)/256,256,0,stream>>>(bihf_c, bhhf_c, biasgf, 1200);
  k_biassum<<<(1200+255)/256,256,0,stream>>>(bihb_c, bhhb_c, biasgb, 1200);
  k_biascvt<<<3,256,0,stream>>>(bq_c, bqf, 600);
  k_biascvt<<<3,256,0,stream>>>(bk_c, bkf, 600);
  k_biascvt<<<3,256,0,stream>>>(g1b_c, gc1bf, 600);
  k_biascvt<<<3,256,0,stream>>>(g2b_c, gc2bf, 600);

  // --- input projections (embs @ Wih^T + bias) ---
  gemm_k<1,1><<<dim3(128,10,1),256,0,stream>>>(16384,1200,336, embs,336,0, wihpf,336,0,
        nullptr, gi_f,1200,0, biasgf,0,nullptr,nullptr);
  gemm_k<1,1><<<dim3(128,10,1),256,0,stream>>>(16384,1200,336, embs,336,0, wihpb,336,0,
        nullptr, gi_b,1200,0, biasgb,0,nullptr,nullptr);

  // --- BiLSTM: one launch, communication-free, 128 blocks ---
  lstm_block_k<<<128,256,0,stream>>>(gi_f, gi_b, whhpf, whhpb, textout, text_len);

  // --- q/k projections, head-scattered (dk padded 100->104) ---
  hipMemsetAsync(qh, 0, 20447232, stream);
  hipMemsetAsync(kh, 0, 20447232, stream);
  gemm_k<1,2><<<dim3(128,5,1),256,0,stream>>>(16384,600,600, textout,600,0, wq_c,600,0,
        nullptr, qh,0,0, bqf,0,nullptr,nullptr);
  gemm_k<1,2><<<dim3(128,5,1),256,0,stream>>>(16384,600,600, textout,600,0, wk_c,600,0,
        nullptr, kh,0,0, bkf,0,nullptr,nullptr);

  // --- attention scores + mask ---
  gemm_k<1,3><<<dim3(1,1,768),256,0,stream>>>(128,128,104, qh,104,13312, kh,104,13312,
        scores, nullptr, 128, 16384, nullptr,0,nullptr, nonpad);

  // --- entmax15 (in place) ---
  k_entmax<<<98304,64,0,stream>>>(scores);

  // --- adjacency: head-mean + eye + valid; degree norms ---
  k_adjsem<<<(2097152+255)/256,256,0,stream>>>(scores, nonpad, adj_sem);
  k_dn<<<16384,64,0,stream>>>(adj_sem, dn1);
  k_dn<<<16384,64,0,stream>>>(adj_c, dn2);

  // --- SE #1 + GCN #1 (norm folded: Z = D (A (D * se * X))) ---
  k_mean<<<16384,64,0,stream>>>(textout, ymean);
  k_senet<<<128,128,0,stream>>>(ymean, sw1_c,sb1_c,sw2_c,sb2_c, nonpad, ysoft);
  k_scale2<<<(9830400+255)/256,256,0,stream>>>(textout, ysoft, dn1, se_x);
  gemm_k<0,1><<<dim3(1,5,128),256,0,stream>>>(128,600,128, adj_sem,128,16384, se_x,600,76800,
        nullptr, Zb,600,76800, nullptr,0, dn1, nullptr);
  gemm_k<0,1><<<dim3(128,5,1),256,0,stream>>>(16384,600,600, Zb,600,0, g1w_c,600,0,
        nullptr, x_sem,600,0, gc1bf,1,nullptr,nullptr);

  // --- SE #2 + GCN #2 (uses input adj) ---
  k_mean<<<16384,64,0,stream>>>(x_sem, ymean);
  k_senet<<<128,128,0,stream>>>(ymean, sw1_c,sb1_c,sw2_c,sb2_c, nonpad, ysoft);
  k_scale2<<<(9830400+255)/256,256,0,stream>>>(x_sem, ysoft, dn2, se_x);
  gemm_k<0,1><<<dim3(1,5,128),256,0,stream>>>(128,600,128, adj_c,128,16384, se_x,600,76800,
        nullptr, Zb,600,76800, nullptr,0, dn2, nullptr);
  gemm_k<0,1><<<dim3(128,5,1),256,0,stream>>>(16384,600,600, Zb,600,0, g2w_c,600,0,
        nullptr, xb,600,0, gc2bf,1,nullptr,nullptr);

  // --- biaffine pooling (only row left_len[b] of A1/A2 is ever used) ---
  k_gather<<<128,128,0,stream>>>(xb, left_len, xr);
  k_gather<<<128,128,0,stream>>>(x_sem, left_len, xsr);
  gemm_k<0,1><<<dim3(1,5,1),256,0,stream>>>(128,600,600, xr,600,0, af1_c,600,0,
        nullptr, g1,600,0, nullptr,0,nullptr,nullptr);
  gemm_k<0,1><<<dim3(1,5,1),256,0,stream>>>(128,600,600, xsr,600,0, af2_c,600,0,
        nullptr, g2,600,0, nullptr,0,nullptr,nullptr);
  k_pool<<<128,256,0,stream>>>(g1, x_sem, pooled, 0);
  k_pool<<<128,256,0,stream>>>(g2, xb, pooled, 600);

  // --- final FC (dtype-adaptive output) ---
  k_final<<<128,64,0,stream>>>(pooled, fcw_c, fcb_c, d_out, probe);
}

// Round 10
// 3802.406 us; speedup vs baseline: 2.5697x; 1.0351x over previous
//
#include <hip/hip_runtime.h>

typedef unsigned short ushort_t;
typedef unsigned int   uint_t;
typedef __attribute__((ext_vector_type(8))) short short8;
typedef __attribute__((ext_vector_type(4))) float floatx4;

#define NEGV -1000000000.0f

__device__ __forceinline__ float bf2f(ushort_t h){ return __uint_as_float(((uint_t)h)<<16); }
__device__ __forceinline__ ushort_t f2bf(float f){
  uint_t u = __float_as_uint(f);
  uint_t r = u + 0x7fffu + ((u>>16)&1u);
  return (ushort_t)(r>>16);
}
__device__ __forceinline__ float wredsum(float v){ for(int o=32;o;o>>=1) v += __shfl_xor(v,o); return v; }
__device__ __forceinline__ float wredmax(float v){ for(int o=32;o;o>>=1) v = fmaxf(v,__shfl_xor(v,o)); return v; }
__device__ __forceinline__ int   wredsumi(int v){ for(int o=32;o;o>>=1) v += __shfl_xor(v,o); return v; }

// ---------------------------------------------------------------------------
// dtype-adaptive conversion, vectorized x8. Probe once per block in wave 0.
// ---------------------------------------------------------------------------
__global__ void k_cvt8(const void* __restrict__ src, ushort_t* __restrict__ dst,
                       long n, const ushort_t* __restrict__ probe_src){
  __shared__ int sflag;
  if (threadIdx.x < 64){
    ushort_t u = probe_src[2*threadIdx.x];
    int e = (u>>7)&0xFF;
    int c = (e>=100 && e<=140) ? 1 : 0;
    c = wredsumi(c);
    if (threadIdx.x==0) sflag = (c>32) ? 1 : 0;
  }
  __syncthreads();
  bool isbf = (sflag!=0);
  long base = (blockIdx.x*256L + threadIdx.x)*8;
  if (base>=n) return;
  if (isbf){
    if (base+8<=n) *(uint4*)(dst+base) = *(const uint4*)((const ushort_t*)src+base);
    else for (long i=base;i<n;i++) dst[i]=((const ushort_t*)src)[i];
  } else {
    const float* s = (const float*)src;
    if (base+8<=n){
      float4 v0 = *(const float4*)(s+base);
      float4 v1 = *(const float4*)(s+base+4);
      ushort_t o[8] = {f2bf(v0.x),f2bf(v0.y),f2bf(v0.z),f2bf(v0.w),
                       f2bf(v1.x),f2bf(v1.y),f2bf(v1.z),f2bf(v1.w)};
      *(uint4*)(dst+base) = *(uint4*)o;
    } else {
      for (long i=base;i<n;i++) dst[i]=f2bf(s[i]);
    }
  }
}

__device__ __forceinline__ bool probe_is_bf16(const ushort_t* probe_src){
  int c=0;
  #pragma unroll 1
  for (int i=0;i<64;i++){
    ushort_t u = probe_src[2*i];
    int e = (u>>7)&0xFF;
    c += (e>=100 && e<=140) ? 1 : 0;
  }
  return c>32;
}

// ---------------------------------------------------------------------------
// small prep kernels
// ---------------------------------------------------------------------------
__global__ void k_lens(const int* __restrict__ ti, const int* __restrict__ li,
                       int* __restrict__ nonpad, int* __restrict__ text_len,
                       int* __restrict__ left_len){
  int b = blockIdx.x, t = threadIdx.x;
  nonpad[b*128+t] = (ti[b*128+t]!=0) ? 1 : 0;
  if (t==0){
    int c=0; for (int k2=0;k2<128;k2++) c += (ti[b*128+k2]!=0);
    text_len[b]=c;
    int l=0; for (int k2=0;k2<24;k2++) l += (li[b*24+k2]!=0);
    left_len[b]=l;
  }
}

__global__ void k_aspmean(const int* __restrict__ ai, const ushort_t* __restrict__ em,
                          float* __restrict__ asp_mean){
  int b = blockIdx.x;
  int idxs[5]; int cnt=0;
  for (int a=0;a<5;a++){ int ix=ai[b*5+a]; idxs[a]=ix; cnt += (ix!=0); }
  float inv = 1.0f/(float)cnt;
  for (int d=threadIdx.x; d<300; d+=128){
    float s=0.f;
    for (int a=0;a<5;a++) if (idxs[a]) s += bf2f(em[(long)idxs[a]*300+d]);
    asp_mean[b*300+d] = s*inv;
  }
}

__global__ void k_embs(const int* __restrict__ ti, const int* __restrict__ pi,
                       const int* __restrict__ asp_post,
                       const ushort_t* __restrict__ em, const ushort_t* __restrict__ pe,
                       const float* __restrict__ asp_mean, ushort_t* __restrict__ embs){
  int blk = blockIdx.x;
  int b = blk>>7, t = blk&127;
  int ap = asp_post[b];
  int tix = ti[b*128+t];
  int pix = pi[b*128+t];
  for (int col=threadIdx.x; col<336; col+=128){
    ushort_t v;
    if (col<300) v = (t==ap) ? f2bf(asp_mean[b*300+col]) : em[(long)tix*300+col];
    else if (col<330) v = pe[pix*30 + (col-300)];
    else v = 0;
    embs[(long)(b*128+t)*336 + col] = v;
  }
}

__global__ void k_padcopy(const ushort_t* __restrict__ src, ushort_t* __restrict__ dst,
                          int rows, int sk, int dk){
  int i = blockIdx.x*blockDim.x + threadIdx.x;
  int n = rows*dk;
  if (i<n){
    int r = i/dk, c2 = i - r*dk;
    dst[i] = (c2<sk) ? src[r*sk+c2] : 0;
  }
}

// Whh repack: dst[4][304][320], per-gate rows padded 300->304, K 300->320, zeros.
__global__ void k_padwhh(const ushort_t* __restrict__ src, ushort_t* __restrict__ dst){
  int i = blockIdx.x*blockDim.x + threadIdx.x;
  if (i >= 1216*320) return;
  int r = i/320, k = i - r*320;
  int gate = r/304, jj = r - gate*304;
  ushort_t v = 0;
  if (jj<300 && k<300) v = src[(long)(gate*300+jj)*300 + k];
  dst[i] = v;
}

__global__ void k_biassum(const ushort_t* __restrict__ a, const ushort_t* __restrict__ b,
                          float* __restrict__ dst, int n){
  int i = blockIdx.x*blockDim.x + threadIdx.x;
  if (i<n) dst[i] = bf2f(a[i]) + bf2f(b[i]);
}
__global__ void k_biascvt(const ushort_t* __restrict__ a, float* __restrict__ dst, int n){
  int i = blockIdx.x*blockDim.x + threadIdx.x;
  if (i<n) dst[i] = bf2f(a[i]);
}

// ---------------------------------------------------------------------------
// generic bf16 MFMA GEMM: 128x128 tile, 4 waves (2x2), each 64x64 via 4x4
// frags of 16x16x32.  TB=1: C = A * B^T.  TB=0: C = A * B.
// MODE 1: bf16 store (opt bias/relu/rowscale)
// MODE 2: qk head-scatter bf16 store (bias), T=128, dk=100->104
// MODE 3: f32 store, *0.1 and nonpad column mask (attention scores)
// ---------------------------------------------------------------------------
template<int TB, int MODE>
__global__ __launch_bounds__(256) void gemm_k(
    int M, int N, int K,
    const ushort_t* __restrict__ A, long lda, long sAz,
    const ushort_t* __restrict__ B, long ldb, long sBz,
    float* __restrict__ Cf, ushort_t* __restrict__ Cb, long ldc, long sCz,
    const float* __restrict__ bias, int relu,
    const float* __restrict__ rowscale,
    const int* __restrict__ nonpad)
{
  __shared__ ushort_t As[128*40];
  __shared__ ushort_t Bs[128*40];
  const int tid = threadIdx.x;
  const int m0 = blockIdx.x*128, n0 = blockIdx.y*128;
  const int z = blockIdx.z;
  const ushort_t* Ap = A + (long)z*sAz;
  const ushort_t* Bp = B + (long)z*sBz;
  floatx4 acc[4][4];
  #pragma unroll
  for (int i=0;i<4;i++)
    #pragma unroll
    for (int j=0;j<4;j++){ acc[i][j][0]=0.f; acc[i][j][1]=0.f; acc[i][j][2]=0.f; acc[i][j][3]=0.f; }
  const int w = tid>>6, wm = w&1, wn = w>>1;
  const int lane = tid&63, lr = lane&15, lq = lane>>4;

  for (int k0=0;k0<K;k0+=32){
    #pragma unroll
    for (int c2=0;c2<2;c2++){
      int ch = tid + 256*c2;
      int row = ch>>2, kc = (ch&3)*8;
      int gr = m0+row, gk = k0+kc;
      uint4 v{};
      if (gr<M && gk<K) v = *(const uint4*)(Ap + (long)gr*lda + gk);
      *(uint4*)(&As[row*40+kc]) = v;
    }
    if (TB){
      #pragma unroll
      for (int c2=0;c2<2;c2++){
        int ch = tid + 256*c2;
        int row = ch>>2, kc = (ch&3)*8;
        int gn = n0+row, gk = k0+kc;
        uint4 v{};
        if (gn<N && gk<K) v = *(const uint4*)(Bp + (long)gn*ldb + gk);
        int sw = kc ^ (((row>>3)&3)<<3);
        *(uint4*)(&Bs[row*40+sw]) = v;
      }
    } else {
      #pragma unroll
      for (int c2=0;c2<2;c2++){
        int ch = tid + 256*c2;
        int kk = ch>>4, nc = (ch&15)*8;
        int gk = k0+kk, gn = n0+nc;
        uint4 v{};
        if (gk<K && gn<N) v = *(const uint4*)(Bp + (long)gk*ldb + gn);
        uint_t wsv[4] = {v.x, v.y, v.z, v.w};
        #pragma unroll
        for (int e=0;e<8;e++){
          ushort_t hv = (e&1) ? (ushort_t)(wsv[e>>1]>>16) : (ushort_t)(wsv[e>>1]&0xffffu);
          int n = nc+e;
          int sw = kk ^ (((n>>3)&3)<<3);
          Bs[n*40+sw] = hv;
        }
      }
    }
    __syncthreads();
    short8 af[4], bfv[4];
    #pragma unroll
    for (int i=0;i<4;i++) af[i] = *(const short8*)(&As[(wm*64+i*16+lr)*40 + lq*8]);
    #pragma unroll
    for (int j=0;j<4;j++){
      int n = wn*64+j*16+lr;
      int sw = (lq*8) ^ (((n>>3)&3)<<3);
      bfv[j] = *(const short8*)(&Bs[n*40+sw]);
    }
    #pragma unroll
    for (int i=0;i<4;i++)
      #pragma unroll
      for (int j=0;j<4;j++)
        acc[i][j] = __builtin_amdgcn_mfma_f32_16x16x32_bf16(af[i], bfv[j], acc[i][j], 0,0,0);
    __syncthreads();
  }

  #pragma unroll
  for (int i=0;i<4;i++){
    #pragma unroll
    for (int j=0;j<4;j++){
      #pragma unroll
      for (int r=0;r<4;r++){
        int row = m0 + wm*64 + i*16 + lq*4 + r;
        int col = n0 + wn*64 + j*16 + lr;
        if (row<M && col<N){
          float v = acc[i][j][r];
          if (rowscale) v *= rowscale[(long)z*M + row];
          if (bias) v += bias[col];
          if (relu && v<0.f) v = 0.f;
          if (MODE==1){
            Cb[(long)z*sCz + (long)row*ldc + col] = f2bf(v);
          } else if (MODE==2){
            int b = row>>7, t = row&127;
            int h = col/100, d = col - h*100;
            Cb[ ((long)((b*6+h)*128+t))*104 + d ] = f2bf(v);
          } else if (MODE==3){
            v *= 0.1f;
            if (!nonpad[(z/6)*128 + col]) v = NEGV;
            Cf[(long)z*sCz + (long)row*ldc + col] = v;
          }
        }
      }
    }
  }
}

// ---------------------------------------------------------------------------
// Communication-free BiLSTM, MLP-provisioned: grid 128 = 64 batch-pairs x
// 2 dirs; block 512 (8 waves = 2/SIMD). Wave w: gate = w&3, j-half = w>>2
// (10 or 9 j-tiles of 16). A (Whh) loaded directly from L2-resident global
// with nt-level double buffer; B (h, 2 valid cols) from LDS. h in LDS,
// c in regs. No atomics / grid barrier / cross-block state.
// whh layout: [4][304][320].
// ---------------------------------------------------------------------------
__global__ __launch_bounds__(512) void lstm_block_k(
    const ushort_t* __restrict__ gi_f, const ushort_t* __restrict__ gi_b,
    const ushort_t* __restrict__ whh_f, const ushort_t* __restrict__ whh_b,
    ushort_t* __restrict__ text_out, const int* __restrict__ text_len)
{
  const int bx = blockIdx.x;
  const int dir = bx>>6, bg = bx&63;
  const ushort_t* gi  = dir ? gi_b  : gi_f;
  const ushort_t* whh = dir ? whh_b : whh_f;

  __shared__ __align__(16) ushort_t h_lds[2][328];
  __shared__ __align__(16) float    g_lds[4][2][304];
  __shared__ int s_tlen[2];

  const int tid = threadIdx.x;
  const int w = tid>>6, lane = tid&63, lr = lane&15, lq = lane>>4;
  const int gate = w&3, jh = w>>2;
  const int nt0 = jh*10;                 // tile offset: 0 or 10
  const int ntn = jh ? 9 : 10;           // tiles this wave owns

  for (int i=tid; i<2*328; i+=512) ((ushort_t*)h_lds)[i] = 0;
  if (tid<2) s_tlen[tid] = text_len[bg*2+tid];
  float c_reg[2]; c_reg[0]=0.f; c_reg[1]=0.f;
  __syncthreads();

  const ushort_t* wbase = whh + (long)gate*304*320;

  for (int s=0; s<128; s++){
    const int t = dir ? (127-s) : s;

    // gi register prefetch (independent; overlaps MFMA phase)
    ushort_t gp[2][4];
    #pragma unroll
    for (int it=0; it<2; it++){
      int item = tid + it*512;
      if (item<600){
        int b = item/300, j = item - b*300;
        long gb = ((long)((bg*2+b)*128 + t))*1200 + j;
        gp[it][0] = gi[gb];
        gp[it][1] = gi[gb+300];
        gp[it][2] = gi[gb+600];
        gp[it][3] = gi[gb+900];
      }
    }

    // B fragments: h rows (cols 0..1 valid, rest zero)
    short8 bfv[10];
    #pragma unroll
    for (int kt=0; kt<10; kt++){
      short8 z = {0,0,0,0,0,0,0,0};
      bfv[kt] = (lr<2) ? *(const short8*)(&h_lds[lr][kt*32 + lq*8]) : z;
    }

    // MFMA over ntn j-tiles, double-buffered A loads
    short8 a0[10], a1[10];
    {
      const ushort_t* ar = wbase + (long)((nt0)*16 + lr)*320 + lq*8;
      #pragma unroll
      for (int kt=0; kt<10; kt++) a0[kt] = *(const short8*)(ar + kt*32);
    }
    #pragma unroll 1
    for (int nt=0; nt<ntn; nt++){
      if (nt+1<ntn){
        const ushort_t* an = wbase + (long)((nt0+nt+1)*16 + lr)*320 + lq*8;
        #pragma unroll
        for (int kt=0; kt<10; kt++) a1[kt] = *(const short8*)(an + kt*32);
      }
      floatx4 acc; acc[0]=0.f; acc[1]=0.f; acc[2]=0.f; acc[3]=0.f;
      #pragma unroll
      for (int kt=0; kt<10; kt++)
        acc = __builtin_amdgcn_mfma_f32_16x16x32_bf16(a0[kt], bfv[kt], acc, 0,0,0);
      if (lr<2) *(float4*)(&g_lds[gate][lr][(nt0+nt)*16 + lq*4]) = *(float4*)&acc;
      #pragma unroll
      for (int kt=0; kt<10; kt++) a0[kt] = a1[kt];
    }
    __syncthreads();

    // epilogue: gates, c (regs) / h (LDS) update, text_out store
    #pragma unroll
    for (int it=0; it<2; it++){
      int item = tid + it*512;
      if (item<600){
        int b = item/300, j = item - b*300;
        float g_i = g_lds[0][b][j] + bf2f(gp[it][0]);
        float g_f = g_lds[1][b][j] + bf2f(gp[it][1]);
        float g_g = g_lds[2][b][j] + bf2f(gp[it][2]);
        float g_o = g_lds[3][b][j] + bf2f(gp[it][3]);
        float ig = 1.f/(1.f+expf(-g_i));
        float fg = 1.f/(1.f+expf(-g_f));
        float gg = tanhf(g_g);
        float og = 1.f/(1.f+expf(-g_o));
        float cn = fg*c_reg[it] + ig*gg;
        float hn = og*tanhf(cn);
        int m = (t < s_tlen[b]) ? 1 : 0;
        if (m) c_reg[it] = cn;
        float hold = bf2f(h_lds[b][j]);
        float hv = m ? hn : hold;
        h_lds[b][j] = f2bf(hv);
        text_out[((long)((bg*2+b)*128+t))*600 + dir*300 + j] = f2bf(m ? hn : 0.f);
      }
    }
    __syncthreads();
  }
}

// ---------------------------------------------------------------------------
// entmax15 over rows of 128 (in-place on f32 scores). 1 wave per row.
// ---------------------------------------------------------------------------
__global__ __launch_bounds__(64) void k_entmax(float* __restrict__ p){
  long row = blockIdx.x;
  float* base = p + row*128;
  __shared__ float xo[128], xs[128], c1[128], c2[128];
  int t = threadIdx.x;
  float a = base[t]*0.5f, b = base[t+64]*0.5f;
  float m = wredmax(fmaxf(a,b));
  a -= m; b -= m;
  xo[t]=a; xo[t+64]=b; xs[t]=a; xs[t+64]=b;
  __syncthreads();
  for (int k2=2;k2<=128;k2<<=1){
    for (int j=k2>>1;j>0;j>>=1){
      int i = ((t & ~(j-1))<<1) | (t & (j-1));
      int ixj = i | j;
      float vi = xs[i], vj = xs[ixj];
      bool blk = (i & k2)==0;
      bool sw = blk ? (vi < vj) : (vi > vj);
      __syncthreads();
      if (sw){ xs[i]=vj; xs[ixj]=vi; }
      __syncthreads();
    }
  }
  c1[t]=xs[t];       c2[t]=xs[t]*xs[t];
  c1[t+64]=xs[t+64]; c2[t+64]=xs[t+64]*xs[t+64];
  __syncthreads();
  for (int d=1; d<128; d<<=1){
    float a1 = (t>=d)     ? c1[t-d]    : 0.f;
    float a2 = (t>=d)     ? c2[t-d]    : 0.f;
    float b1 = (t+64>=d)  ? c1[t+64-d] : 0.f;
    float b2 = (t+64>=d)  ? c2[t+64-d] : 0.f;
    float x1=c1[t], y1=c2[t], x2=c1[t+64], y2=c2[t+64];
    __syncthreads();
    c1[t]=x1+a1; c2[t]=y1+a2; c1[t+64]=x2+b1; c2[t+64]=y2+b2;
    __syncthreads();
  }
  float tau_a, tau_b; int cnt=0;
  {
    float rho = (float)(t+1);
    float mean = c1[t]/rho, msq = c2[t]/rho;
    float ss = rho*(msq-mean*mean);
    float delta = (1.f-ss)/rho;
    tau_a = mean - sqrtf(fmaxf(delta,0.f));
    cnt += (tau_a <= xs[t]) ? 1 : 0;
  }
  {
    float rho = (float)(t+65);
    float mean = c1[t+64]/rho, msq = c2[t+64]/rho;
    float ss = rho*(msq-mean*mean);
    float delta = (1.f-ss)/rho;
    tau_b = mean - sqrtf(fmaxf(delta,0.f));
    cnt += (tau_b <= xs[t+64]) ? 1 : 0;
  }
  __syncthreads();
  c1[t]=tau_a; c1[t+64]=tau_b;
  __syncthreads();
  int support = wredsumi(cnt);
  support = (support<1) ? 1 : ((support>128) ? 128 : support);
  float tau_star = c1[support-1];
  float oa = fmaxf(xo[t]-tau_star, 0.f);
  float ob = fmaxf(xo[t+64]-tau_star, 0.f);
  base[t] = oa*oa; base[t+64] = ob*ob;
}

// ---------------------------------------------------------------------------
__global__ void k_adjsem(const float* __restrict__ p, const int* __restrict__ nonpad,
                         ushort_t* __restrict__ adj_sem){
  int idx = blockIdx.x*blockDim.x + threadIdx.x;
  if (idx >= 128*128*128) return;
  int b = idx>>14, rem = idx&16383, i = rem>>7, j = rem&127;
  float s = 0.f;
  for (int h=0;h<6;h++) s += p[(long)b*98304 + h*16384 + i*128 + j];
  float v = s/6.0f;
  if (i==j) v = 1.0f;
  if (!nonpad[b*128+i]) v = 0.f;
  adj_sem[idx] = f2bf(v);
}

__global__ __launch_bounds__(64) void k_dn(const ushort_t* __restrict__ src, float* __restrict__ dnv){
  long row = blockIdx.x;
  int l = threadIdx.x;
  float s = bf2f(src[row*128+l]) + bf2f(src[row*128+l+64]);
  s = wredsum(s);
  if (l==0) dnv[row] = 1.0f/sqrtf(s+1.0f);
}

__global__ __launch_bounds__(64) void k_mean(const ushort_t* __restrict__ X, float* __restrict__ ymean){
  long row = blockIdx.x;
  float s=0.f;
  for (int d=threadIdx.x; d<600; d+=64) s += bf2f(X[row*600+d]);
  s = wredsum(s);
  if (threadIdx.x==0) ymean[row] = s/600.0f;
}

__global__ void k_senet(const float* __restrict__ ymean,
                        const ushort_t* __restrict__ w1, const ushort_t* __restrict__ b1,
                        const ushort_t* __restrict__ w2, const ushort_t* __restrict__ b2,
                        const int* __restrict__ nonpad, float* __restrict__ ysoft){
  int b = blockIdx.x, t = threadIdx.x;
  __shared__ float yv[128], z1[12], red[128];
  yv[t] = ymean[b*128+t];
  __syncthreads();
  if (t<12){
    float s = bf2f(b1[t]);
    for (int k2=0;k2<128;k2++) s += yv[k2]*bf2f(w1[t*128+k2]);
    z1[t] = fmaxf(s,0.f);
  }
  __syncthreads();
  float v = bf2f(b2[t]);
  for (int r=0;r<12;r++) v += z1[r]*bf2f(w2[t*12+r]);
  if (!nonpad[b*128+t]) v += NEGV;
  red[t]=v; __syncthreads();
  for (int s2=64;s2>0;s2>>=1){ if (t<s2) red[t]=fmaxf(red[t],red[t+s2]); __syncthreads(); }
  float mx = red[0]; __syncthreads();
  float e = expf(v-mx);
  red[t]=e; __syncthreads();
  for (int s2=64;s2>0;s2>>=1){ if (t<s2) red[t]+=red[t+s2]; __syncthreads(); }
  float sm = red[0];
  ysoft[b*128+t] = e/sm;
}

__global__ void k_scale2(const ushort_t* __restrict__ X, const float* __restrict__ ysoft,
                         const float* __restrict__ dnv, ushort_t* __restrict__ out){
  int i = blockIdx.x*blockDim.x + threadIdx.x;
  if (i >= 128*128*600) return;
  int row = i/600;
  out[i] = f2bf(bf2f(X[i])*ysoft[row]*dnv[row]);
}

__global__ void k_gather(const ushort_t* __restrict__ X, const int* __restrict__ left_len,
                         ushort_t* __restrict__ dst){
  int b = blockIdx.x;
  int lb = left_len[b];
  for (int d=threadIdx.x; d<600; d+=128)
    dst[b*600+d] = X[(long)(b*128+lb)*600+d];
}

__global__ __launch_bounds__(256) void k_pool(const ushort_t* __restrict__ g,
                                              const ushort_t* __restrict__ X,
                                              float* __restrict__ pooled, int poff){
  int b = blockIdx.x, tid = threadIdx.x;
  __shared__ float gs[600], sbuf[128], red[256];
  for (int d=tid; d<600; d+=256) gs[d] = bf2f(g[b*600+d]);
  __syncthreads();
  int wv = tid>>6, lane = tid&63;
  for (int jj=wv; jj<128; jj+=4){
    float s=0.f;
    for (int d=lane; d<600; d+=64) s += gs[d]*bf2f(X[(long)(b*128+jj)*600+d]);
    s = wredsum(s);
    if (lane==0) sbuf[jj]=s;
  }
  __syncthreads();
  float v = (tid<128) ? sbuf[tid] : -3.4e38f;
  red[tid]=v; __syncthreads();
  for (int s2=128;s2>0;s2>>=1){ if (tid<s2) red[tid]=fmaxf(red[tid],red[tid+s2]); __syncthreads(); }
  float mx = red[0]; __syncthreads();
  float e = (tid<128) ? expf(v-mx) : 0.f;
  red[tid]=e; __syncthreads();
  for (int s2=128;s2>0;s2>>=1){ if (tid<s2) red[tid]+=red[tid+s2]; __syncthreads(); }
  float sm = red[0]; __syncthreads();
  if (tid<128) sbuf[tid] = e/sm;
  __syncthreads();
  for (int d=tid; d<600; d+=256){
    float acc=0.f;
    for (int j=0;j<128;j++) acc += sbuf[j]*bf2f(X[(long)(b*128+j)*600+d]);
    pooled[(long)b*1200 + poff + d] = acc;
  }
}

__global__ __launch_bounds__(64) void k_final(const float* __restrict__ pooled,
                                              const ushort_t* __restrict__ fcw,
                                              const ushort_t* __restrict__ fcb,
                                              void* __restrict__ out,
                                              const ushort_t* __restrict__ probe_src){
  bool isbf = probe_is_bf16(probe_src);
  int b = blockIdx.x, lane = threadIdx.x;
  for (int p=0;p<3;p++){
    float s=0.f;
    for (int d=lane; d<1200; d+=64) s += pooled[(long)b*1200+d]*bf2f(fcw[d*3+p]);
    s = wredsum(s);
    if (lane==0){
      float r = s + bf2f(fcb[p]);
      if (isbf) ((ushort_t*)out)[b*3+p] = f2bf(r);
      else      ((float*)out)[b*3+p] = r;
    }
  }
}

// ---------------------------------------------------------------------------
extern "C" void kernel_launch(void* const* d_in, const int* in_sizes, int n_in,
                              void* d_out, int out_size, void* d_ws, size_t ws_size,
                              hipStream_t stream) {
  const int*      ti   = (const int*)d_in[0];
  const int*      ai   = (const int*)d_in[1];
  const int*      li   = (const int*)d_in[2];
  const int*      pi   = (const int*)d_in[3];
  const int*      aps  = (const int*)d_in[4];
  const ushort_t* probe = (const ushort_t*)d_in[7];

  char* w = (char*)d_ws; size_t off = 0;
  auto alloc = [&](size_t bytes)->char*{ char* p = w+off; off = (off+bytes+255)&~(size_t)255; return p; };

  int*   text_len = (int*)alloc(512);
  int*   left_len = (int*)alloc(512);
  int*   nonpad   = (int*)alloc(65536);
  float* asp_mean = (float*)alloc(153600);
  float* dn1      = (float*)alloc(65536);
  float* dn2      = (float*)alloc(65536);
  float* ymean    = (float*)alloc(65536);
  float* ysoft    = (float*)alloc(65536);
  ushort_t* wihpf = (ushort_t*)alloc(806400);
  ushort_t* wihpb = (ushort_t*)alloc(806400);
  ushort_t* whhpf = (ushort_t*)alloc(778240);   // [4][304][320]
  ushort_t* whhpb = (ushort_t*)alloc(778240);
  float* biasgf   = (float*)alloc(4800);
  float* biasgb   = (float*)alloc(4800);
  float* bqf      = (float*)alloc(2400);
  float* bkf      = (float*)alloc(2400);
  float* gc1bf    = (float*)alloc(2400);
  float* gc2bf    = (float*)alloc(2400);
  ushort_t* g1    = (ushort_t*)alloc(153600);
  ushort_t* g2    = (ushort_t*)alloc(153600);
  ushort_t* xr    = (ushort_t*)alloc(153600);
  ushort_t* xsr   = (ushort_t*)alloc(153600);
  float* pooled   = (float*)alloc(614400);
  ushort_t* adj_c  = (ushort_t*)alloc(4194304);
  ushort_t* pe_c   = (ushort_t*)alloc(2048);
  ushort_t* wihf_c = (ushort_t*)alloc(792000);
  ushort_t* wihb_c = (ushort_t*)alloc(792000);
  ushort_t* whhf_c = (ushort_t*)alloc(720000);
  ushort_t* whhb_c = (ushort_t*)alloc(720000);
  ushort_t* bihf_c = (ushort_t*)alloc(2400);
  ushort_t* bhhf_c = (ushort_t*)alloc(2400);
  ushort_t* bihb_c = (ushort_t*)alloc(2400);
  ushort_t* bhhb_c = (ushort_t*)alloc(2400);
  ushort_t* wq_c   = (ushort_t*)alloc(720000);
  ushort_t* bq_c   = (ushort_t*)alloc(1200);
  ushort_t* wk_c   = (ushort_t*)alloc(720000);
  ushort_t* bk_c   = (ushort_t*)alloc(1200);
  ushort_t* sw1_c  = (ushort_t*)alloc(3072);
  ushort_t* sb1_c  = (ushort_t*)alloc(256);
  ushort_t* sw2_c  = (ushort_t*)alloc(3072);
  ushort_t* sb2_c  = (ushort_t*)alloc(256);
  ushort_t* g1w_c  = (ushort_t*)alloc(720000);
  ushort_t* g1b_c  = (ushort_t*)alloc(1200);
  ushort_t* g2w_c  = (ushort_t*)alloc(720000);
  ushort_t* g2b_c  = (ushort_t*)alloc(1200);
  ushort_t* af1_c  = (ushort_t*)alloc(720000);
  ushort_t* af2_c  = (ushort_t*)alloc(720000);
  ushort_t* fcw_c  = (ushort_t*)alloc(7200);
  ushort_t* fcb_c  = (ushort_t*)alloc(256);
  ushort_t* embs  = (ushort_t*)alloc(11010048);
  ushort_t* textout = (ushort_t*)alloc(19660800);
  char* R = alloc(95420416);
  ushort_t* em_c    = (ushort_t*)(R);            // 18 MB; dead after k_embs
  ushort_t* gi_f    = (ushort_t*)(R);
  ushort_t* gi_b    = (ushort_t*)(R+39321600);
  ushort_t* qh      = (ushort_t*)(R);
  ushort_t* kh      = (ushort_t*)(R+20447232);
  float*    scores  = (float*)(R+40894464);
  ushort_t* adj_sem = (ushort_t*)(R+91226112);
  ushort_t* se_x    = (ushort_t*)(R+40894464);
  ushort_t* Zb      = (ushort_t*)(R+60555264);
  ushort_t* x_sem   = (ushort_t*)(R);
  ushort_t* xb      = (ushort_t*)(R+20447232);
  (void)ws_size; (void)n_in; (void)in_sizes; (void)out_size;

  // --- normalize all float inputs to bf16 (cheap per-block probe, x8 vec) ---
  {
    const int idx[27] = {7,6, 8,9,13,10,14,11,12,15,16,17,18,19,20,21,22,23,24,25,26,27,28,29,30,31,32};
    ushort_t* dl[27] = {em_c,adj_c, pe_c,wihf_c,wihb_c,whhf_c,whhb_c,bihf_c,bhhf_c,bihb_c,bhhb_c,
                        wq_c,bq_c,wk_c,bk_c,sw1_c,sb1_c,sw2_c,sb2_c,
                        g1w_c,g1b_c,g2w_c,g2b_c,af1_c,af2_c,fcw_c,fcb_c};
    const long nl[27] = {9000000L,2097152L, 900,396000,396000,360000,360000,1200,1200,1200,1200,
                         360000,600,360000,600,1536,12,1536,128,
                         360000,600,360000,600,360000,360000,3600,3};
    for (int i=0;i<27;i++){
      long nb = ((nl[i]+7)/8 + 255)/256;
      k_cvt8<<<(int)nb,256,0,stream>>>(d_in[idx[i]], dl[i], nl[i], probe);
    }
  }

  // --- prep ---
  k_lens<<<128,128,0,stream>>>(ti, li, nonpad, text_len, left_len);
  k_aspmean<<<128,128,0,stream>>>(ai, em_c, asp_mean);
  k_embs<<<16384,128,0,stream>>>(ti, pi, aps, em_c, pe_c, asp_mean, embs);
  k_padcopy<<<(1200*336+255)/256,256,0,stream>>>(wihf_c, wihpf, 1200, 330, 336);
  k_padcopy<<<(1200*336+255)/256,256,0,stream>>>(wihb_c, wihpb, 1200, 330, 336);
  k_padwhh<<<(1216*320+255)/256,256,0,stream>>>(whhf_c, whhpf);
  k_padwhh<<<(1216*320+255)/256,256,0,stream>>>(whhb_c, whhpb);
  k_biassum<<<(1200+255)/256,256,0,stream>>>(bihf_c, bhhf_c, biasgf, 1200);
  k_biassum<<<(1200+255)/256,256,0,stream>>>(bihb_c, bhhb_c, biasgb, 1200);
  k_biascvt<<<3,256,0,stream>>>(bq_c, bqf, 600);
  k_biascvt<<<3,256,0,stream>>>(bk_c, bkf, 600);
  k_biascvt<<<3,256,0,stream>>>(g1b_c, gc1bf, 600);
  k_biascvt<<<3,256,0,stream>>>(g2b_c, gc2bf, 600);

  // --- input projections (embs @ Wih^T + bias) ---
  gemm_k<1,1><<<dim3(128,10,1),256,0,stream>>>(16384,1200,336, embs,336,0, wihpf,336,0,
        nullptr, gi_f,1200,0, biasgf,0,nullptr,nullptr);
  gemm_k<1,1><<<dim3(128,10,1),256,0,stream>>>(16384,1200,336, embs,336,0, wihpb,336,0,
        nullptr, gi_b,1200,0, biasgb,0,nullptr,nullptr);

  // --- BiLSTM: one launch, communication-free, 128 blocks x 512 threads ---
  lstm_block_k<<<128,512,0,stream>>>(gi_f, gi_b, whhpf, whhpb, textout, text_len);

  // --- q/k projections, head-scattered (dk padded 100->104) ---
  hipMemsetAsync(qh, 0, 20447232, stream);
  hipMemsetAsync(kh, 0, 20447232, stream);
  gemm_k<1,2><<<dim3(128,5,1),256,0,stream>>>(16384,600,600, textout,600,0, wq_c,600,0,
        nullptr, qh,0,0, bqf,0,nullptr,nullptr);
  gemm_k<1,2><<<dim3(128,5,1),256,0,stream>>>(16384,600,600, textout,600,0, wk_c,600,0,
        nullptr, kh,0,0, bkf,0,nullptr,nullptr);

  // --- attention scores + mask ---
  gemm_k<1,3><<<dim3(1,1,768),256,0,stream>>>(128,128,104, qh,104,13312, kh,104,13312,
        scores, nullptr, 128, 16384, nullptr,0,nullptr, nonpad);

  // --- entmax15 (in place) ---
  k_entmax<<<98304,64,0,stream>>>(scores);

  // --- adjacency: head-mean + eye + valid; degree norms ---
  k_adjsem<<<(2097152+255)/256,256,0,stream>>>(scores, nonpad, adj_sem);
  k_dn<<<16384,64,0,stream>>>(adj_sem, dn1);
  k_dn<<<16384,64,0,stream>>>(adj_c, dn2);

  // --- SE #1 + GCN #1 (norm folded: Z = D (A (D * se * X))) ---
  k_mean<<<16384,64,0,stream>>>(textout, ymean);
  k_senet<<<128,128,0,stream>>>(ymean, sw1_c,sb1_c,sw2_c,sb2_c, nonpad, ysoft);
  k_scale2<<<(9830400+255)/256,256,0,stream>>>(textout, ysoft, dn1, se_x);
  gemm_k<0,1><<<dim3(1,5,128),256,0,stream>>>(128,600,128, adj_sem,128,16384, se_x,600,76800,
        nullptr, Zb,600,76800, nullptr,0, dn1, nullptr);
  gemm_k<0,1><<<dim3(128,5,1),256,0,stream>>>(16384,600,600, Zb,600,0, g1w_c,600,0,
        nullptr, x_sem,600,0, gc1bf,1,nullptr,nullptr);

  // --- SE #2 + GCN #2 (uses input adj) ---
  k_mean<<<16384,64,0,stream>>>(x_sem, ymean);
  k_senet<<<128,128,0,stream>>>(ymean, sw1_c,sb1_c,sw2_c,sb2_c, nonpad, ysoft);
  k_scale2<<<(9830400+255)/256,256,0,stream>>>(x_sem, ysoft, dn2, se_x);
  gemm_k<0,1><<<dim3(1,5,128),256,0,stream>>>(128,600,128, adj_c,128,16384, se_x,600,76800,
        nullptr, Zb,600,76800, nullptr,0, dn2, nullptr);
  gemm_k<0,1><<<dim3(128,5,1),256,0,stream>>>(16384,600,600, Zb,600,0, g2w_c,600,0,
        nullptr, xb,600,0, gc2bf,1,nullptr,nullptr);

  // --- biaffine pooling (only row left_len[b] of A1/A2 is ever used) ---
  k_gather<<<128,128,0,stream>>>(xb, left_len, xr);
  k_gather<<<128,128,0,stream>>>(x_sem, left_len, xsr);
  gemm_k<0,1><<<dim3(1,5,1),256,0,stream>>>(128,600,600, xr,600,0, af1_c,600,0,
        nullptr, g1,600,0, nullptr,0,nullptr,nullptr);
  gemm_k<0,1><<<dim3(1,5,1),256,0,stream>>>(128,600,600, xsr,600,0, af2_c,600,0,
        nullptr, g2,600,0, nullptr,0,nullptr,nullptr);
  k_pool<<<128,256,0,stream>>>(g1, x_sem, pooled, 0);
  k_pool<<<128,256,0,stream>>>(g2, xb, pooled, 600);

  // --- final FC (dtype-adaptive output) ---
  k_final<<<128,64,0,stream>>>(pooled, fcw_c, fcb_c, d_out, probe);
}